// Round 11
// baseline (654.334 us; speedup 1.0000x reference)
//
#include <hip/hip_runtime.h>
#include <hip/hip_bf16.h>
#include <math.h>

typedef float f32x4 __attribute__((ext_vector_type(4)));
typedef short s16x8 __attribute__((ext_vector_type(8)));
typedef short s16x4 __attribute__((ext_vector_type(4)));
typedef unsigned int u32;

#define DEVI __device__ __forceinline__

// ---- sizes ----
#define Bn   8
#define Sn   512
#define Hn   1024
#define Tn   8
#define Kn   2
#define FFn  4096
#define NHn  8
#define HDn  128
#define Ln   1024            // K*S
#define OUT_COMBINED 4194304 // B*S*H

DEVI unsigned short f2bf(float x) {
  __hip_bfloat16 h = __float2bfloat16(x);
  union { __hip_bfloat16 h; unsigned short u; } cv; cv.h = h; return cv.u;
}
DEVI float bf2f(unsigned short u) {
  union { u32 i; float f; } cv; cv.i = ((u32)u) << 16; return cv.f;
}
// tanh-form GELU: |err| vs exact erf-GELU < 1e-3 (bf16 eps dominates)
DEVI float gelu_f(float x) {
  float t = x * x * x;
  float y = 0.7978845608028654f * x + 0.03567740813f * t;
  float e = exp2f(2.8853900817779268f * y);      // e^{2y}
  return x - x / (e + 1.0f);                      // x * e/(e+1)
}

typedef __attribute__((address_space(3))) u32 lds_u32;
typedef __attribute__((address_space(1))) u32 glb_u32;
DEVI void gload16(const void* g, void* l) {
  __builtin_amdgcn_global_load_lds((const glb_u32*)g, (lds_u32*)l, 16, 0, 0);
}

// ---------------- pool (mean over S) — reads bf16 (after cvt) ----------------
__global__ __launch_bounds__(256) void pool_part_k(const unsigned short* __restrict__ hid, float* __restrict__ part)
{
  const int b = blockIdx.x, scn = blockIdx.y;
  const int hh = threadIdx.x * 4;
  float4 acc = make_float4(0.f, 0.f, 0.f, 0.f);
  const unsigned short* base = hid + ((long)b * Sn + (long)scn * 128) * Hn + hh;
  for (int s = 0; s < 128; ++s) {
    s16x4 v = *(const s16x4*)(base + (long)s * Hn);
    acc.x += bf2f((unsigned short)v[0]); acc.y += bf2f((unsigned short)v[1]);
    acc.z += bf2f((unsigned short)v[2]); acc.w += bf2f((unsigned short)v[3]);
  }
  *(float4*)(part + ((long)(scn * Bn + b)) * Hn + hh) = acc;
}

__global__ __launch_bounds__(256) void pool_final_k(const float* __restrict__ part, float* __restrict__ pooled)
{
  const int i = blockIdx.x * 256 + threadIdx.x;
  float s = 0.f;
  for (int sc = 0; sc < 4; ++sc) s += part[sc * (Bn * Hn) + i];
  pooled[i] = s * (1.f / (float)Sn);
}

// ---------------- router + entropy (parallel dot: 256 threads) ----------------
__global__ __launch_bounds__(256) void router_k(
    const float* __restrict__ pooled, const float* __restrict__ rw, const float* __restrict__ rb,
    float* __restrict__ probs, int* __restrict__ topi, float* __restrict__ wts,
    int* __restrict__ flags, float* __restrict__ entropy_out)
{
  __shared__ float partial[256];
  __shared__ float lg[64];
  __shared__ int sfl[8];
  __shared__ float sent[8];
  const int tid = threadIdx.x;
  const int bt = tid & 63, slice = tid >> 6;
  const int b = bt >> 3, t = bt & 7;
  if (tid < 8) sfl[tid] = 0;
  float acc = 0.f;
  const float* pb = pooled + b * Hn;
  for (int i = slice * 256; i < slice * 256 + 256; ++i) acc += pb[i] * rw[i * Tn + t];
  partial[tid] = acc;
  __syncthreads();
  if (tid < 64) lg[tid] = rb[t] + partial[tid] + partial[tid + 64] + partial[tid + 128] + partial[tid + 192];
  __syncthreads();
  if (tid < 64 && t == 0) {
    float p[8];
    float mx = lg[b * 8];
    for (int i = 1; i < 8; ++i) mx = fmaxf(mx, lg[b * 8 + i]);
    float ssum = 0.f;
    for (int i = 0; i < 8; ++i) { p[i] = expf(lg[b * 8 + i] - mx); ssum += p[i]; }
    float ent = 0.f;
    for (int i = 0; i < 8; ++i) { p[i] /= ssum; ent -= p[i] * logf(p[i] + 1e-8f); probs[b * 8 + i] = p[i]; }
    sent[b] = ent;
    int i1 = 0;
    for (int i = 1; i < 8; ++i) if (p[i] > p[i1]) i1 = i;   // strict > : lowest index on ties (lax.top_k)
    int i2 = (i1 == 0) ? 1 : 0;
    for (int i = 0; i < 8; ++i) if (i != i1 && p[i] > p[i2]) i2 = i;
    float w0 = 1.f / (1.f + expf(p[i2] - p[i1]));
    float w1 = 1.f / (1.f + expf(p[i1] - p[i2]));
    topi[b * 2] = i1; topi[b * 2 + 1] = i2;
    wts[b * 2] = w0; wts[b * 2 + 1] = w1;
    atomicOr(&sfl[i1], 1); atomicOr(&sfl[i2], 1);
  }
  __syncthreads();
  if (tid < 8) flags[tid] = sfl[tid];
  if (tid == 0) {
    float e = 0.f;
    for (int i = 0; i < 8; ++i) e += sent[i];
    entropy_out[0] = e * (1.f / (float)Bn);
  }
}

// ---------------- f32 -> bf16 convert ----------------
__global__ __launch_bounds__(256) void cvt_k(const float* __restrict__ in, unsigned short* __restrict__ out)
{
  const long i = ((long)blockIdx.x * 256 + threadIdx.x) * 4;
  float4 v = *(const float4*)(in + i);
  s16x4 o;
  o[0] = (short)f2bf(v.x); o[1] = (short)f2bf(v.y); o[2] = (short)f2bf(v.z); o[3] = (short)f2bf(v.w);
  *(s16x4*)(out + i) = o;
}

// ---------------- bias concat for fused QKV ----------------
__global__ __launch_bounds__(256) void bias3_k(const float* __restrict__ bq, const float* __restrict__ bk,
                                               const float* __restrict__ bv, float* __restrict__ o)
{
  const int i = blockIdx.x * 256 + threadIdx.x;   // 0..1023
  o[i] = bq[i]; o[i + 1024] = bk[i]; o[i + 2048] = bv[i];
}

// ---------------- transpose+convert: in f32 [Kd][N] -> out bf16 [N][Kd], 64x64 tiles ----------------
__global__ __launch_bounds__(256) void transpose_k(const float* __restrict__ Win, unsigned short* __restrict__ Wout,
                                                   int Kd, int N, long sIn, long sOut, const int* __restrict__ flags)
{
  const int t = blockIdx.z;
  if (flags && flags[t] == 0) return;   // uniform per block
  __shared__ float tile[64][65];
  const float* in = Win + (long)t * sIn;
  unsigned short* out = Wout + (long)t * sOut;
  const int kb = blockIdx.y * 64, nb = blockIdx.x * 64;
  const int tx = threadIdx.x & 15, ty = threadIdx.x >> 4;
  #pragma unroll
  for (int i = 0; i < 4; ++i) {
    const int r = ty + i * 16;
    float4 v = *(const float4*)(in + (long)(kb + r) * N + nb + tx * 4);
    tile[r][tx * 4 + 0] = v.x; tile[r][tx * 4 + 1] = v.y;
    tile[r][tx * 4 + 2] = v.z; tile[r][tx * 4 + 3] = v.w;
  }
  __syncthreads();
  #pragma unroll
  for (int i = 0; i < 4; ++i) {
    const int n = ty + i * 16;
    s16x4 o;
    #pragma unroll
    for (int j = 0; j < 4; ++j) o[j] = (short)f2bf(tile[tx * 4 + j][n]);
    *(s16x4*)(out + (long)(nb + n) * Kd + kb + tx * 4) = o;
  }
}

// ---------------- GEMM (A-direct-to-reg): C[M,N] = A[M,Kd] @ Bt[N,Kd]^T + bias ----------------
// BM=256, BN=128, BK=32. 4 waves (2M x 2N), wave tile 128x64.
// A: fragment-direct inline-asm global_load_dwordx4 into double-buffered regs
//    (arE/arO; per-wave-exclusive data -> LDS staging buys nothing).
// B: LDS DMA, 3 buffers (24KB), shared across the wm-pair.
// Per-tile VMEM issue order (pinned by side-effecting DMA + asm volatile):
//   [2 B-DMA(kt+2)] -> [8 A-loads(kt+1)] -> [4 ds_read(kt)].
// Pre-MFMA wait vmcnt(10/8/0): retires A(kt) AND (transitively) B(kt+1), which
// was issued before A(kt) -> next tile's ds_reads safe after the boundary barrier.
// sched_barrier(0) after waits (asm-lgkm + MFMA hoisting hazard).
// LDS/wave/K-tile: 4KB (was 12KB) -> LDS pipe no longer 3x oversubscribed.
// T1 bijective XCD remap. EPI 1 = tanh-GELU. OUTMODE 1 = fused QKV.
template<int EPI, int OUTMODE>
__global__ __launch_bounds__(256, 2) void gemmR_k(
    const unsigned short* __restrict__ A0, const unsigned short* __restrict__ Bt0,
    const float* __restrict__ bias0, unsigned short* __restrict__ C0,
    int N, int Kd,
    const int* __restrict__ topi, int kTop,
    long sA_b, long sA_p, long sBt_t, int sBias_t, long sC_p)
{
  __shared__ __align__(16) char smem[36864];
  char* const Bb = smem;              // 3 x 8192 (128 rows x 64B); epilogue reuses all

  // ---- T1 bijective XCD tile remap ----
  const int gx = gridDim.x, gy = gridDim.y;
  const int nwg = gx * gy * gridDim.z;
  const int hw = blockIdx.x + gx * (blockIdx.y + gy * blockIdx.z);
  const int q = nwg >> 3, r = nwg & 7;
  const int xcd = hw & 7, sub = hw >> 3;
  int lin = (xcd < r ? xcd * (q + 1) : r * (q + 1) + (xcd - r) * q) + sub;
  const int bx = lin % gx; lin /= gx;
  const int by = lin % gy;
  const int bz = lin / gy;

  const int bidx = kTop ? (bz / kTop) : 0;
  const int te = topi ? topi[bz] : 0;
  const unsigned short* A = A0 + (long)bidx * sA_b + (long)bz * sA_p;
  const unsigned short* Bt = Bt0 + (long)te * sBt_t;
  const float* bias = bias0 + (long)te * sBias_t;
  unsigned short* C = C0 + (long)bz * sC_p;

  const int m0 = by * 256;
  const int n0 = bx * 128;
  const int tid = threadIdx.x;
  const int lane = tid & 63, w = tid >> 6;
  const int wm = w >> 1, wn = w & 1;
  const int rA = lane & 15, g = lane >> 4;

  // ---- B staging source (pre-swizzled global chunk, f(r) = (r>>1)&3) ----
  const int sr = lane >> 2;
  const int sc = lane & 3;
  const int csw = (sc ^ ((sr >> 1) & 3)) * 8;
  const unsigned short* gBw = Bt + (long)(n0 + w * 32 + sr) * Kd + csw;
  const int ldso = lane << 4;

  // ---- B fragment LDS byte offsets (swizzled read, same f) ----
  const int sl = (rA >> 1) & 3;
  int boff[4];
  #pragma unroll
  for (int nj = 0; nj < 4; ++nj)
    boff[nj] = (wn * 64 + nj * 16 + rA) * 64 + ((g ^ sl) << 4);

  // ---- A fragment-direct per-lane global pointers (advance by kt*32 shorts) ----
  const unsigned short* pA[8];
  #pragma unroll
  for (int mi = 0; mi < 8; ++mi)
    pA[mi] = A + (long)(m0 + wm * 128 + mi * 16 + rA) * Kd + g * 8;

  f32x4 acc[8][4];
  const f32x4 zero = {0.f, 0.f, 0.f, 0.f};
  #pragma unroll
  for (int i = 0; i < 8; ++i)
    #pragma unroll
    for (int j = 0; j < 4; ++j) acc[i][j] = zero;

  const int nt = Kd >> 5;

  auto stageB = [&](int kt2, int buf, int i) {
    gload16(gBw + (long)i * 16 * Kd + kt2 * 32, Bb + buf * 8192 + w * 2048 + i * 1024 + ldso);
  };

  s16x8 arE[8], arO[8];

  // ---- prologue: B(0),B(1) DMA then A(0) loads; vmcnt(10) retires B(0) ----
  stageB(0, 0, 0); stageB(0, 0, 1);
  stageB(1, 1, 0); stageB(1, 1, 1);
  #pragma unroll
  for (int mi = 0; mi < 8; ++mi)
    asm volatile("global_load_dwordx4 %0, %1, off" : "=v"(arE[mi]) : "v"(pA[mi]) : "memory");
  asm volatile("s_waitcnt vmcnt(10)" ::: "memory");
  __builtin_amdgcn_s_barrier();

  auto tile = [&](int kt, s16x8 (&cur)[8], s16x8 (&nxt)[8]) {
    const char* pb = Bb + (kt % 3) * 8192;
    const bool stB = (kt + 2 < nt);
    if (stB) {
      const int fb = (kt + 2) % 3;
      stageB(kt + 2, fb, 0); stageB(kt + 2, fb, 1);
    }
    if (kt + 1 < nt) {
      #pragma unroll
      for (int mi = 0; mi < 8; ++mi)
        asm volatile("global_load_dwordx4 %0, %1, off"
                     : "=v"(nxt[mi]) : "v"(pA[mi] + (kt + 1) * 32) : "memory");
    }
    s16x8 bf[4];
    #pragma unroll
    for (int nj = 0; nj < 4; ++nj) bf[nj] = *(const s16x8*)(pb + boff[nj]);
    // A(kt) retired (and transitively B(kt+1)); bf data drained
    if (stB)              asm volatile("s_waitcnt vmcnt(10) lgkmcnt(0)" ::: "memory");
    else if (kt + 1 < nt) asm volatile("s_waitcnt vmcnt(8) lgkmcnt(0)" ::: "memory");
    else                  asm volatile("s_waitcnt vmcnt(0) lgkmcnt(0)" ::: "memory");
    __builtin_amdgcn_sched_barrier(0);
    __builtin_amdgcn_s_setprio(1);
    #pragma unroll
    for (int mi = 0; mi < 8; ++mi)
      #pragma unroll
      for (int nj = 0; nj < 4; ++nj)
        acc[mi][nj] = __builtin_amdgcn_mfma_f32_16x16x32_bf16(cur[mi], bf[nj], acc[mi][nj], 0, 0, 0);
    __builtin_amdgcn_s_setprio(0);
    __builtin_amdgcn_sched_barrier(0);
    __builtin_amdgcn_s_barrier();
  };

  for (int kt = 0; kt < nt; kt += 2) {
    tile(kt, arE, arO);
    tile(kt + 1, arO, arE);
  }

  __syncthreads();   // drain before LDS reuse for epilogue

  // ---- epilogue via per-wave LDS tiles (two 64x64 parts, pitch 72 shorts) ----
  unsigned short* et = (unsigned short*)(smem + w * 9216);
  const int r4 = g << 2;
  const int nbase = n0 + wn * 64;
  const int seg = (OUTMODE == 1) ? (nbase >> 10) : 0;
  const int erow = lane >> 3, echunk = lane & 7;
  float bv[4];
  #pragma unroll
  for (int nj = 0; nj < 4; ++nj) bv[nj] = bias[nbase + nj * 16 + rA];

  #pragma unroll
  for (int p = 0; p < 2; ++p) {
    #pragma unroll
    for (int nj = 0; nj < 4; ++nj) {
      #pragma unroll
      for (int mi2 = 0; mi2 < 4; ++mi2) {
        #pragma unroll
        for (int j = 0; j < 4; ++j) {
          float x = acc[p * 4 + mi2][nj][j] + bv[nj];
          if (EPI == 1) x = gelu_f(x);
          const int mrl = mi2 * 16 + r4 + j;
          const int ncl = nj * 16 + rA;
          if (OUTMODE == 0 || seg < 2) et[mrl * 72 + ncl] = f2bf(x);
          else                         et[ncl * 72 + mrl] = f2bf(x);
        }
      }
    }
    const long mrow0 = m0 + wm * 128 + p * 64;
    if (OUTMODE == 0) {
      #pragma unroll
      for (int rr = 0; rr < 8; ++rr) {
        const int row = rr * 8 + erow;
        s16x8 v = *(const s16x8*)(et + row * 72 + echunk * 8);
        *(s16x8*)(C + (mrow0 + row) * N + nbase + echunk * 8) = v;
      }
    } else {
      const int nseg = nbase & 1023;
      if (seg < 2) {
        unsigned short* dst = C + (long)seg * 8388608;
        #pragma unroll
        for (int rr = 0; rr < 8; ++rr) {
          const int row = rr * 8 + erow;
          s16x8 v = *(const s16x8*)(et + row * 72 + echunk * 8);
          *(s16x8*)(dst + (mrow0 + row) * 1024 + nseg + echunk * 8) = v;
        }
      } else {
        unsigned short* vtp = C + 16777216;
        const int bb = (int)(mrow0 >> 10);
        const int ltok0 = (int)(mrow0 & 1023);
        #pragma unroll
        for (int rr = 0; rr < 8; ++rr) {
          const int nrow = rr * 8 + erow;
          s16x8 v = *(const s16x8*)(et + nrow * 72 + echunk * 8);
          *(s16x8*)(vtp + ((long)(bb * 1024 + nseg + nrow)) * 1024 + ltok0 + echunk * 8) = v;
        }
      }
    }
  }
}

// ---------------- flash attention v3 ----------------
__global__ __launch_bounds__(256) void flash_k(
    const unsigned short* __restrict__ q, const unsigned short* __restrict__ k,
    const unsigned short* __restrict__ vt, unsigned short* __restrict__ ctx)
{
  __shared__ unsigned short K2[2][64 * 128];  // 2x16KB, [kv][hd] rows 256B, chunk^=(row&7)
  __shared__ unsigned short Vs[128 * 64];     // 16KB, [hd][kv] rows 128B, chunk^=(row&7)
  __shared__ unsigned short Ps[4][32 * 72];   // per-wave P [32 q][64 kv], pitch 72
  const int L = blockIdx.x;
  const int qt = L >> 6;
  const int hb = (((L >> 3) & 7) << 3) + (L & 7);
  const int h = hb & 7, b = hb >> 3;
  const int tid = threadIdx.x, lane = tid & 63, w = tid >> 6;
  const int rA = lane & 15, g = lane >> 4;
  const int q0w = qt * 128 + w * 32;

  s16x8 qf[2][4];
  #pragma unroll
  for (int qi = 0; qi < 2; ++qi) {
    const unsigned short* qp = q + ((long)(b * Ln + q0w + qi * 16 + rA)) * Hn + h * HDn + g * 8;
    #pragma unroll
    for (int kk = 0; kk < 4; ++kk) qf[qi][kk] = *(const s16x8*)(qp + kk * 32);
  }
  asm volatile("s_waitcnt vmcnt(0)" ::: "memory");   // drain Q: vmcnt now counts only gload16

  f32x4 o[2][8];
  const f32x4 zero = {0.f, 0.f, 0.f, 0.f};
  #pragma unroll
  for (int qi = 0; qi < 2; ++qi)
    #pragma unroll
    for (int nn = 0; nn < 8; ++nn) o[qi][nn] = zero;
  float lrun[2][4];
  #pragma unroll
  for (int qi = 0; qi < 2; ++qi)
    #pragma unroll
    for (int j = 0; j < 4; ++j) lrun[qi][j] = 0.f;
  float m = 0.f;

  const float sc2 = 0.08838834764831845f * 1.4426950408889634f;  // 1/sqrt(128)*log2(e)

  const int krow0 = w * 16 + g;
  const int kc = lane & 15;
  const int vrow0 = w * 32 + (lane >> 3);
  const int vc = lane & 7;

  const unsigned short* kp[4];
  const unsigned short* vp[4];
  #pragma unroll
  for (int qq = 0; qq < 4; ++qq) {
    const int rk = krow0 + qq * 4;
    kp[qq] = k + ((long)(b * Ln + rk)) * Hn + h * HDn + ((kc ^ (rk & 7)) * 8);
    const int rv = vrow0 + qq * 8;
    vp[qq] = vt + ((long)(b * 1024 + h * HDn + rv)) * Ln + ((vc ^ (rv & 7)) * 8);
  }

  auto issueK = [&](int buf) {
    #pragma unroll
    for (int qq = 0; qq < 4; ++qq) {
      gload16(kp[qq], (char*)K2[buf] + w * 4096 + qq * 1024);
      kp[qq] += 64 * Hn;
    }
  };
  auto issueV = [&]() {
    #pragma unroll
    for (int qq = 0; qq < 4; ++qq) {
      gload16(vp[qq], (char*)Vs + w * 4096 + qq * 1024);
      vp[qq] += 64;
    }
  };

  issueK(0);
  asm volatile("s_waitcnt vmcnt(0)" ::: "memory");
  __builtin_amdgcn_s_barrier();

  for (int kvt = 0; kvt < 16; ++kvt) {
    const bool st = (kvt + 1 < 16);
    const char* Kcur = (const char*)K2[kvt & 1];
    issueV();
    if (st) issueK((kvt + 1) & 1);

    f32x4 sacc[2][4];
    #pragma unroll
    for (int qi = 0; qi < 2; ++qi)
      #pragma unroll
      for (int nj = 0; nj < 4; ++nj) sacc[qi][nj] = zero;
    __builtin_amdgcn_s_setprio(1);
    #pragma unroll
    for (int kk = 0; kk < 4; ++kk) {
      #pragma unroll
      for (int nj = 0; nj < 4; ++nj) {
        const int row = nj * 16 + rA;
        const int byt = row * 256 + (((kk * 4 + g) ^ (row & 7)) << 4);
        s16x8 kf = *(const s16x8*)(Kcur + byt);
        sacc[0][nj] = __builtin_amdgcn_mfma_f32_16x16x32_bf16(qf[0][kk], kf, sacc[0][nj], 0, 0, 0);
        sacc[1][nj] = __builtin_amdgcn_mfma_f32_16x16x32_bf16(qf[1][kk], kf, sacc[1][nj], 0, 0, 0);
      }
    }
    __builtin_amdgcn_s_setprio(0);

    float t8[8];
    #pragma unroll
    for (int qi = 0; qi < 2; ++qi)
      #pragma unroll
      for (int nj = 0; nj < 4; ++nj) {
        float s0 = sacc[qi][nj][0] * sc2;
        float s1 = sacc[qi][nj][1] * sc2;
        float s2 = sacc[qi][nj][2] * sc2;
        float s3 = sacc[qi][nj][3] * sc2;
        sacc[qi][nj][0] = s0; sacc[qi][nj][1] = s1;
        sacc[qi][nj][2] = s2; sacc[qi][nj][3] = s3;
        t8[qi * 4 + nj] = fmaxf(fmaxf(s0, s1), fmaxf(s2, s3));
      }
    const float vmax = fmaxf(fmaxf(fmaxf(t8[0], t8[1]), fmaxf(t8[2], t8[3])),
                             fmaxf(fmaxf(t8[4], t8[5]), fmaxf(t8[6], t8[7])));
    if (!__all(vmax <= m + 8.0f)) {
      float mn = vmax;
      #pragma unroll
      for (int mm = 1; mm < 64; mm <<= 1) mn = fmaxf(mn, __shfl_xor(mn, mm, 64));
      const float al = exp2f(m - mn);
      #pragma unroll
      for (int qi = 0; qi < 2; ++qi) {
        #pragma unroll
        for (int nn = 0; nn < 8; ++nn)
          #pragma unroll
          for (int j = 0; j < 4; ++j) o[qi][nn][j] *= al;
        #pragma unroll
        for (int j = 0; j < 4; ++j) lrun[qi][j] *= al;
      }
      m = mn;
    }

    #pragma unroll
    for (int qi = 0; qi < 2; ++qi)
      #pragma unroll
      for (int j = 0; j < 4; ++j) {
        float p0 = exp2f(sacc[qi][0][j] - m);
        float p1 = exp2f(sacc[qi][1][j] - m);
        float p2 = exp2f(sacc[qi][2][j] - m);
        float p3 = exp2f(sacc[qi][3][j] - m);
        lrun[qi][j] += (p0 + p1) + (p2 + p3);
        const int prow = (qi * 16 + g * 4 + j) * 72;
        Ps[w][prow + 0 * 16 + rA] = f2bf(p0);
        Ps[w][prow + 1 * 16 + rA] = f2bf(p1);
        Ps[w][prow + 2 * 16 + rA] = f2bf(p2);
        Ps[w][prow + 3 * 16 + rA] = f2bf(p3);
      }

    if (st) asm volatile("s_waitcnt vmcnt(4)" ::: "memory");
    else    asm volatile("s_waitcnt vmcnt(0)" ::: "memory");
    __builtin_amdgcn_s_barrier();

    s16x8 pf[2][2];
    #pragma unroll
    for (int qi = 0; qi < 2; ++qi)
      #pragma unroll
      for (int kk2 = 0; kk2 < 2; ++kk2)
        pf[qi][kk2] = *(const s16x8*)(&Ps[w][(qi * 16 + rA) * 72 + kk2 * 32 + g * 8]);
    __builtin_amdgcn_s_setprio(1);
    #pragma unroll
    for (int kk2 = 0; kk2 < 2; ++kk2) {
      #pragma unroll
      for (int nn = 0; nn < 8; ++nn) {
        const int row = nn * 16 + rA;
        const int byt = row * 128 + (((kk2 * 4 + g) ^ (row & 7)) << 4);
        s16x8 vf = *(const s16x8*)((const char*)Vs + byt);
        o[0][nn] = __builtin_amdgcn_mfma_f32_16x16x32_bf16(pf[0][kk2], vf, o[0][nn], 0, 0, 0);
        o[1][nn] = __builtin_amdgcn_mfma_f32_16x16x32_bf16(pf[1][kk2], vf, o[1][nn], 0, 0, 0);
      }
    }
    __builtin_amdgcn_s_setprio(0);

    if (st) asm volatile("s_waitcnt vmcnt(0) lgkmcnt(0)" ::: "memory");
    else    asm volatile("s_waitcnt lgkmcnt(0)" ::: "memory");
    __builtin_amdgcn_s_barrier();
  }

  float linv[2][4];
  #pragma unroll
  for (int qi = 0; qi < 2; ++qi)
    #pragma unroll
    for (int j = 0; j < 4; ++j) {
      float l = lrun[qi][j];
      #pragma unroll
      for (int mm = 1; mm < 16; mm <<= 1) l += __shfl_xor(l, mm, 64);
      linv[qi][j] = 1.0f / l;
    }
  #pragma unroll
  for (int qi = 0; qi < 2; ++qi)
    #pragma unroll
    for (int nn = 0; nn < 8; ++nn)
      #pragma unroll
      for (int j = 0; j < 4; ++j) {
        const int row = q0w + qi * 16 + g * 4 + j;
        ctx[((long)(b * Ln + row)) * Hn + h * HDn + nn * 16 + rA] = f2bf(o[qi][nn][j] * linv[qi][j]);
      }
}

// ---------------- diversity ----------------
__global__ __launch_bounds__(256) void div_part_k(const unsigned short* __restrict__ br, float* __restrict__ part)
{
  const int b = blockIdx.y, ch = blockIdx.x;
  const unsigned short* a = br + (long)b * (2L * Sn * Hn);
  const unsigned short* c = a + (long)Sn * Hn;
  const int base = ch * 16384 + threadIdx.x * 8;
  float dot = 0.f, na = 0.f, nb = 0.f;
  #pragma unroll
  for (int i = 0; i < 8; ++i) {
    const int idx = base + i * 2048;
    s16x8 av = *(const s16x8*)(a + idx);
    s16x8 cv = *(const s16x8*)(c + idx);
    #pragma unroll
    for (int e = 0; e < 8; ++e) {
      float fa = bf2f((unsigned short)av[e]);
      float fc = bf2f((unsigned short)cv[e]);
      dot += fa * fc; na += fa * fa; nb += fc * fc;
    }
  }
  #pragma unroll
  for (int mm = 1; mm < 64; mm <<= 1) {
    dot += __shfl_xor(dot, mm, 64);
    na  += __shfl_xor(na, mm, 64);
    nb  += __shfl_xor(nb, mm, 64);
  }
  __shared__ float red[12];
  const int lane = threadIdx.x & 63, w = threadIdx.x >> 6;
  if (lane == 0) { red[w * 3] = dot; red[w * 3 + 1] = na; red[w * 3 + 2] = nb; }
  __syncthreads();
  if (threadIdx.x == 0) {
    float d = 0, x = 0, y = 0;
    for (int i = 0; i < 4; ++i) { d += red[i * 3]; x += red[i * 3 + 1]; y += red[i * 3 + 2]; }
    float* op = part + ((long)(b * 32 + ch)) * 3;
    op[0] = d; op[1] = x; op[2] = y;
  }
}

__global__ __launch_bounds__(64) void div_final_k(const float* __restrict__ part, float* __restrict__ outp)
{
  __shared__ float cosr[8];
  const int tid = threadIdx.x;
  if (tid < 8) {
    float d = 0, x = 0, y = 0;
    for (int i = 0; i < 32; ++i) {
      const float* p = part + ((long)(tid * 32 + i)) * 3;
      d += p[0]; x += p[1]; y += p[2];
    }
    cosr[tid] = d / fmaxf(sqrtf(x) * sqrtf(y), 1e-8f);
  }
  __syncthreads();
  if (tid == 0) {
    float s = 0.f;
    for (int i = 0; i < 8; ++i) s += 1.f - cosr[i];
    outp[0] = s * (1.f / 8.f);
  }
}

// ---------------- weighted combine ----------------
__global__ __launch_bounds__(256) void combine_k(const unsigned short* __restrict__ att,
                                                 const float* __restrict__ wts, float* __restrict__ out)
{
  const long i = ((long)blockIdx.x * 256 + threadIdx.x) * 8;
  const int b = (int)(i >> 19);           // S*H = 524288
  const long rem = i & 524287;
  const unsigned short* a0 = att + (long)b * (2L * Sn * Hn) + rem;
  const unsigned short* a1 = a0 + (long)Sn * Hn;
  const float w0 = wts[b * 2], w1 = wts[b * 2 + 1];
  s16x8 v0 = *(const s16x8*)a0;
  s16x8 v1 = *(const s16x8*)a1;
  float r[8];
  #pragma unroll
  for (int e = 0; e < 8; ++e) r[e] = w0 * bf2f((unsigned short)v0[e]) + w1 * bf2f((unsigned short)v1[e]);
  *(float4*)(out + i)     = make_float4(r[0], r[1], r[2], r[3]);
  *(float4*)(out + i + 4) = make_float4(r[4], r[5], r[6], r[7]);
}

// ---------------- launch ----------------
extern "C" void kernel_launch(void* const* d_in, const int* in_sizes, int n_in,
                              void* d_out, int out_size, void* d_ws, size_t ws_size,
                              hipStream_t stream)
{
  (void)in_sizes; (void)n_in; (void)out_size; (void)ws_size;
  const float* hidden   = (const float*)d_in[0];
  const float* router_w = (const float*)d_in[1];
  const float* router_b = (const float*)d_in[2];
  const float* W1 = (const float*)d_in[3];
  const float* b1 = (const float*)d_in[4];
  const float* W2 = (const float*)d_in[5];
  const float* b2 = (const float*)d_in[6];
  const float* Wq = (const float*)d_in[7];
  const float* bq = (const float*)d_in[8];
  const float* Wk = (const float*)d_in[9];
  const float* bk = (const float*)d_in[10];
  const float* Wv = (const float*)d_in[11];
  const float* bv = (const float*)d_in[12];
  const float* Wo = (const float*)d_in[13];
  const float* bo = (const float*)d_in[14];
  float* out = (float*)d_out;

  char* ws = (char*)d_ws;
  float* pooled  = (float*)(ws);
  float* ppart   = (float*)(ws + 32768);
  float* probs   = (float*)(ws + 163840);
  int*   topi    = (int*)  (ws + 164096);
  float* wts     = (float*)(ws + 164352);
  int*   flags   = (int*)  (ws + 164608);
  float* dpart   = (float*)(ws + 164864);
  float* qkvbias = (float*)(ws + 167936);
  unsigned short* hid_bf = (unsigned short*)(ws + 262144);                           // 8.39MB
  unsigned short* Wt     = (unsigned short*)(ws + 262144 + 8388608);                 // 67.1MB
  unsigned short* hbuf   = (unsigned short*)(ws + 262144 + 8388608 + 67108864);      // 67.1MB
  unsigned short* br     = (unsigned short*)(ws + 262144 + 8388608 + 134217728);     // 16.8MB
  unsigned short* wqkvo  = (unsigned short*)(ws + 262144 + 8388608 + 134217728 + 16777216); // 8.4MB
  unsigned short* qb  = Wt;
  unsigned short* kbf = Wt + 8388608;
  unsigned short* vt  = Wt + 16777216;
  unsigned short* ctx = hbuf;
  unsigned short* att = hbuf + 8388608;
  unsigned short* wqt = wqkvo;
  unsigned short* wkt = wqkvo + 1048576;
  unsigned short* wvt = wqkvo + 2097152;
  unsigned short* wot = wqkvo + 3145728;

  // 1. bf16 convert first (pool reads bf16)
  cvt_k<<<4096, 256, 0, stream>>>(hidden, hid_bf);

  // 2. router path
  pool_part_k<<<dim3(Bn, 4), 256, 0, stream>>>(hid_bf, ppart);
  pool_final_k<<<dim3(32), 256, 0, stream>>>(ppart, pooled);
  router_k<<<1, 256, 0, stream>>>(pooled, router_w, router_b, probs, topi, wts, flags, out + OUT_COMBINED);

  // 3. weight transposes
  bias3_k<<<4, 256, 0, stream>>>(bq, bk, bv, qkvbias);
  transpose_k<<<dim3(64, 16, Tn), 256, 0, stream>>>(W1, Wt, Hn, FFn, (long)Hn * FFn, (long)FFn * Hn, flags);
  transpose_k<<<dim3(16, 16, 1), 256, 0, stream>>>(Wq, wqt, Hn, Hn, 0, 0, nullptr);
  transpose_k<<<dim3(16, 16, 1), 256, 0, stream>>>(Wk, wkt, Hn, Hn, 0, 0, nullptr);
  transpose_k<<<dim3(16, 16, 1), 256, 0, stream>>>(Wv, wvt, Hn, Hn, 0, 0, nullptr);
  transpose_k<<<dim3(16, 16, 1), 256, 0, stream>>>(Wo, wot, Hn, Hn, 0, 0, nullptr);

  // 4. FFN1 (gelu): grid (32,2,16) = 1024 blocks
  gemmR_k<1, 0><<<dim3(FFn / 128, Sn / 256, 16), 256, 0, stream>>>(
      hid_bf, Wt, b1, hbuf, FFn, Hn, topi, 2,
      (long)Sn * Hn, 0L, (long)FFn * Hn, FFn, (long)Sn * FFn);

  // 5. W2 transpose reuses Wt region (W1t dead)
  transpose_k<<<dim3(16, 64, Tn), 256, 0, stream>>>(W2, Wt, FFn, Hn, (long)FFn * Hn, (long)Hn * FFn, flags);

  // 6. FFN2: grid (8,2,16) = 256 blocks
  gemmR_k<0, 0><<<dim3(Hn / 128, Sn / 256, 16), 256, 0, stream>>>(
      hbuf, Wt, b2, br, Hn, FFn, topi, 2,
      0L, (long)Sn * FFn, (long)Hn * FFn, Hn, (long)Sn * Hn);

  // 7. diversity from branch_out
  div_part_k<<<dim3(32, Bn), 256, 0, stream>>>(br, dpart);
  div_final_k<<<1, 64, 0, stream>>>(dpart, out + OUT_COMBINED + 1);

  // 8. fused QKV projection: grid (24,32) = 768 blocks
  gemmR_k<0, 1><<<dim3(3072 / 128, (Bn * Ln) / 256, 1), 256, 0, stream>>>(
      br, wqkvo, qkvbias, qb, 3072, Hn, nullptr, 0, 0L, 0L, 0L, 0, 0L);

  // 9. flash attention v3 (1-D grid, XCD-locality remap)
  flash_k<<<dim3(512), 256, 0, stream>>>(qb, kbf, vt, ctx);

  // 10. output projection: grid (8,32) = 256 blocks
  gemmR_k<0, 0><<<dim3(Hn / 128, (Bn * Ln) / 256, 1), 256, 0, stream>>>(
      ctx, wot, bo, att, Hn, Hn, nullptr, 0, 0L, 0L, 0L, 0, 0L);

  // 11. weighted combine -> f32 output
  combine_k<<<2048, 256, 0, stream>>>(att, wts, out);
}

// Round 12
// 504.091 us; speedup vs baseline: 1.2980x; 1.2980x over previous
//
#include <hip/hip_runtime.h>
#include <hip/hip_bf16.h>
#include <math.h>

typedef float f32x4 __attribute__((ext_vector_type(4)));
typedef short s16x8 __attribute__((ext_vector_type(8)));
typedef short s16x4 __attribute__((ext_vector_type(4)));
typedef unsigned int u32;

#define DEVI __device__ __forceinline__

// ---- sizes ----
#define Bn   8
#define Sn   512
#define Hn   1024
#define Tn   8
#define Kn   2
#define FFn  4096
#define NHn  8
#define HDn  128
#define Ln   1024            // K*S
#define OUT_COMBINED 4194304 // B*S*H

DEVI unsigned short f2bf(float x) {
  __hip_bfloat16 h = __float2bfloat16(x);
  union { __hip_bfloat16 h; unsigned short u; } cv; cv.h = h; return cv.u;
}
DEVI float bf2f(unsigned short u) {
  union { u32 i; float f; } cv; cv.i = ((u32)u) << 16; return cv.f;
}
// tanh-form GELU: |err| vs exact erf-GELU < 1e-3 (bf16 eps dominates)
DEVI float gelu_f(float x) {
  float t = x * x * x;
  float y = 0.7978845608028654f * x + 0.03567740813f * t;
  float e = exp2f(2.8853900817779268f * y);      // e^{2y}
  return x - x / (e + 1.0f);                      // x * e/(e+1)
}

typedef __attribute__((address_space(3))) u32 lds_u32;
typedef __attribute__((address_space(1))) u32 glb_u32;
DEVI void gload16(const void* g, void* l) {
  __builtin_amdgcn_global_load_lds((const glb_u32*)g, (lds_u32*)l, 16, 0, 0);
}

// ---------------- fused f32->bf16 convert + pool partials ----------------
// grid (8,32): each block handles 16 rows of one batch; reads f32 hidden once,
// writes hid_bf AND per-chunk column partial sums (ppart aliases Wt region,
// which is only written later by the W1 transpose -- stream-serial safe).
__global__ __launch_bounds__(256) void poolcvt_k(const float* __restrict__ hid,
                                                 unsigned short* __restrict__ hbf,
                                                 float* __restrict__ part)
{
  const int b = blockIdx.x, scn = blockIdx.y;
  const int hh = threadIdx.x * 4;
  float4 acc = make_float4(0.f, 0.f, 0.f, 0.f);
  const long base = ((long)b * Sn + (long)scn * 16) * Hn + hh;
  for (int s = 0; s < 16; ++s) {
    float4 v = *(const float4*)(hid + base + (long)s * Hn);
    s16x4 o;
    o[0] = (short)f2bf(v.x); o[1] = (short)f2bf(v.y);
    o[2] = (short)f2bf(v.z); o[3] = (short)f2bf(v.w);
    *(s16x4*)(hbf + base + (long)s * Hn) = o;
    acc.x += v.x; acc.y += v.y; acc.z += v.z; acc.w += v.w;
  }
  *(float4*)(part + ((long)(scn * Bn + b)) * Hn + hh) = acc;
}

__global__ __launch_bounds__(256) void pool_final_k(const float* __restrict__ part, float* __restrict__ pooled)
{
  const int i = blockIdx.x * 256 + threadIdx.x;
  float s = 0.f;
  for (int sc = 0; sc < 32; ++sc) s += part[sc * (Bn * Hn) + i];
  pooled[i] = s * (1.f / (float)Sn);
}

// ---------------- router + entropy (parallel dot: 256 threads) ----------------
__global__ __launch_bounds__(256) void router_k(
    const float* __restrict__ pooled, const float* __restrict__ rw, const float* __restrict__ rb,
    float* __restrict__ probs, int* __restrict__ topi, float* __restrict__ wts,
    int* __restrict__ flags, float* __restrict__ entropy_out)
{
  __shared__ float partial[256];
  __shared__ float lg[64];
  __shared__ int sfl[8];
  __shared__ float sent[8];
  const int tid = threadIdx.x;
  const int bt = tid & 63, slice = tid >> 6;
  const int b = bt >> 3, t = bt & 7;
  if (tid < 8) sfl[tid] = 0;
  float acc = 0.f;
  const float* pb = pooled + b * Hn;
  for (int i = slice * 256; i < slice * 256 + 256; ++i) acc += pb[i] * rw[i * Tn + t];
  partial[tid] = acc;
  __syncthreads();
  if (tid < 64) lg[tid] = rb[t] + partial[tid] + partial[tid + 64] + partial[tid + 128] + partial[tid + 192];
  __syncthreads();
  if (tid < 64 && t == 0) {
    float p[8];
    float mx = lg[b * 8];
    for (int i = 1; i < 8; ++i) mx = fmaxf(mx, lg[b * 8 + i]);
    float ssum = 0.f;
    for (int i = 0; i < 8; ++i) { p[i] = expf(lg[b * 8 + i] - mx); ssum += p[i]; }
    float ent = 0.f;
    for (int i = 0; i < 8; ++i) { p[i] /= ssum; ent -= p[i] * logf(p[i] + 1e-8f); probs[b * 8 + i] = p[i]; }
    sent[b] = ent;
    int i1 = 0;
    for (int i = 1; i < 8; ++i) if (p[i] > p[i1]) i1 = i;   // strict > : lowest index on ties (lax.top_k)
    int i2 = (i1 == 0) ? 1 : 0;
    for (int i = 0; i < 8; ++i) if (i != i1 && p[i] > p[i2]) i2 = i;
    float w0 = 1.f / (1.f + expf(p[i2] - p[i1]));
    float w1 = 1.f / (1.f + expf(p[i1] - p[i2]));
    topi[b * 2] = i1; topi[b * 2 + 1] = i2;
    wts[b * 2] = w0; wts[b * 2 + 1] = w1;
    atomicOr(&sfl[i1], 1); atomicOr(&sfl[i2], 1);
  }
  __syncthreads();
  if (tid < 8) flags[tid] = sfl[tid];
  if (tid == 0) {
    float e = 0.f;
    for (int i = 0; i < 8; ++i) e += sent[i];
    entropy_out[0] = e * (1.f / (float)Bn);
  }
}

// ---------------- bias concat for fused QKV ----------------
__global__ __launch_bounds__(256) void bias3_k(const float* __restrict__ bq, const float* __restrict__ bk,
                                               const float* __restrict__ bv, float* __restrict__ o)
{
  const int i = blockIdx.x * 256 + threadIdx.x;   // 0..1023
  o[i] = bq[i]; o[i + 1024] = bk[i]; o[i + 2048] = bv[i];
}

// ---------------- transpose+convert: in f32 [Kd][N] -> out bf16 [N][Kd], 64x64 tiles ----------------
__global__ __launch_bounds__(256) void transpose_k(const float* __restrict__ Win, unsigned short* __restrict__ Wout,
                                                   int Kd, int N, long sIn, long sOut, const int* __restrict__ flags)
{
  const int t = blockIdx.z;
  if (flags && flags[t] == 0) return;   // uniform per block
  __shared__ float tile[64][65];
  const float* in = Win + (long)t * sIn;
  unsigned short* out = Wout + (long)t * sOut;
  const int kb = blockIdx.y * 64, nb = blockIdx.x * 64;
  const int tx = threadIdx.x & 15, ty = threadIdx.x >> 4;
  #pragma unroll
  for (int i = 0; i < 4; ++i) {
    const int r = ty + i * 16;
    float4 v = *(const float4*)(in + (long)(kb + r) * N + nb + tx * 4);
    tile[r][tx * 4 + 0] = v.x; tile[r][tx * 4 + 1] = v.y;
    tile[r][tx * 4 + 2] = v.z; tile[r][tx * 4 + 3] = v.w;
  }
  __syncthreads();
  #pragma unroll
  for (int i = 0; i < 4; ++i) {
    const int n = ty + i * 16;
    s16x4 o;
    #pragma unroll
    for (int j = 0; j < 4; ++j) o[j] = (short)f2bf(tile[tx * 4 + j][n]);
    *(s16x4*)(out + (long)(nb + n) * Kd + kb + tx * 4) = o;
  }
}

// ---------------- GEMM: C[M,N] = A[M,Kd] @ Bt[N,Kd]^T + bias ----------------
// BM=256, BN=128, BK=32. 4 waves (2M x 2N), wave tile 128x64. NBUF=3 (72KB LDS)
// -> 2 blocks/CU. SINGLE barrier per K-tile; counted boundary vmcnt(6)+lgkmcnt(0).
// Swizzle: chunk ^= (row>>1)&3 via pre-swizzled GLOBAL source (LDS dest linear).
// T1 bijective XCD remap. EPI 1 = tanh-GELU. OUTMODE 1 = fused QKV.
template<int EPI, int OUTMODE>
__global__ __launch_bounds__(256, 2) void gemmT_k(
    const unsigned short* __restrict__ A0, const unsigned short* __restrict__ Bt0,
    const float* __restrict__ bias0, unsigned short* __restrict__ C0,
    int N, int Kd,
    const int* __restrict__ topi, int kTop,
    long sA_b, long sA_p, long sBt_t, int sBias_t, long sC_p)
{
  __shared__ __align__(16) char smem[73728];
  char* const Ab = smem;              // 3 x 16384 (256 rows x 64B)
  char* const Bb = smem + 49152;      // 3 x  8192 (128 rows x 64B)

  // ---- T1 bijective XCD tile remap ----
  const int gx = gridDim.x, gy = gridDim.y;
  const int nwg = gx * gy * gridDim.z;
  const int hw = blockIdx.x + gx * (blockIdx.y + gy * blockIdx.z);
  const int q = nwg >> 3, r = nwg & 7;
  const int xcd = hw & 7, sub = hw >> 3;
  int lin = (xcd < r ? xcd * (q + 1) : r * (q + 1) + (xcd - r) * q) + sub;
  const int bx = lin % gx; lin /= gx;
  const int by = lin % gy;
  const int bz = lin / gy;

  const int bidx = kTop ? (bz / kTop) : 0;
  const int te = topi ? topi[bz] : 0;
  const unsigned short* A = A0 + (long)bidx * sA_b + (long)bz * sA_p;
  const unsigned short* Bt = Bt0 + (long)te * sBt_t;
  const float* bias = bias0 + (long)te * sBias_t;
  unsigned short* C = C0 + (long)bz * sC_p;

  const int m0 = by * 256;
  const int n0 = bx * 128;
  const int tid = threadIdx.x;
  const int lane = tid & 63, w = tid >> 6;
  const int wm = w >> 1, wn = w & 1;
  const int rA = lane & 15, g = lane >> 4;

  // ---- staging sources (pre-swizzled global chunk, f(r) = (r>>1)&3) ----
  const int sr = lane >> 2;                 // 0..15 (row within 16-row issue block)
  const int sc = lane & 3;                  // chunk
  const int csw = (sc ^ ((sr >> 1) & 3)) * 8;   // bf16-elem offset
  const unsigned short* gAw = A + (long)(m0 + w * 64 + sr) * Kd + csw;  // + i*16*Kd + kt*32
  const unsigned short* gBw = Bt + (long)(n0 + w * 32 + sr) * Kd + csw;
  const int ldso = lane << 4;

  // ---- fragment LDS byte offsets (swizzled read, same f) ----
  const int sl = (rA >> 1) & 3;
  int aoff[8], boff[4];
  #pragma unroll
  for (int mi = 0; mi < 8; ++mi)
    aoff[mi] = (wm * 128 + mi * 16 + rA) * 64 + ((g ^ sl) << 4);
  #pragma unroll
  for (int nj = 0; nj < 4; ++nj)
    boff[nj] = (wn * 64 + nj * 16 + rA) * 64 + ((g ^ sl) << 4);

  f32x4 acc[8][4];
  const f32x4 zero = {0.f, 0.f, 0.f, 0.f};
  #pragma unroll
  for (int i = 0; i < 8; ++i)
    #pragma unroll
    for (int j = 0; j < 4; ++j) acc[i][j] = zero;

  const int nt = Kd >> 5;

  auto stageA = [&](int kt2, int buf, int i) {
    gload16(gAw + (long)i * 16 * Kd + kt2 * 32, Ab + buf * 16384 + w * 4096 + i * 1024 + ldso);
  };
  auto stageB = [&](int kt2, int buf, int i) {
    gload16(gBw + (long)i * 16 * Kd + kt2 * 32, Bb + buf * 8192 + w * 2048 + i * 1024 + ldso);
  };

  // ---- prologue: stage tiles 0,1 (6 issues each, in order) ----
  #pragma unroll
  for (int j = 0; j < 2; ++j) {
    stageA(j, j, 0); stageA(j, j, 1); stageB(j, j, 0);
    stageA(j, j, 2); stageA(j, j, 3); stageB(j, j, 1);
  }
  asm volatile("s_waitcnt vmcnt(6)" ::: "memory");   // tile 0 landed
  __builtin_amdgcn_s_barrier();

  int cb = 0, fb = 2;
  for (int kt = 0; kt < nt; ++kt) {
    const char* pa = Ab + cb * 16384;
    const char* pb = Bb + cb * 8192;
    const bool st = (kt + 2 < nt);
    const int ft = kt + 2;

    // ---- issue all 12 fragment reads + 6 stage issues; no mid barrier ----
    s16x8 af[8], bf[4];
    #pragma unroll
    for (int mi = 0; mi < 4; ++mi) af[mi] = *(const s16x8*)(pa + aoff[mi]);
    #pragma unroll
    for (int nj = 0; nj < 4; ++nj) bf[nj] = *(const s16x8*)(pb + boff[nj]);
    if (st) { stageA(ft, fb, 0); stageA(ft, fb, 1); stageB(ft, fb, 0); }
    #pragma unroll
    for (int mi = 0; mi < 4; ++mi) af[4 + mi] = *(const s16x8*)(pa + aoff[4 + mi]);
    if (st) { stageA(ft, fb, 2); stageA(ft, fb, 3); stageB(ft, fb, 1); }

    // ---- 32 MFMA (compiler lgkmcnt interleaves remaining reads underneath) ----
    __builtin_amdgcn_s_setprio(1);
    #pragma unroll
    for (int mi = 0; mi < 8; ++mi)
      #pragma unroll
      for (int nj = 0; nj < 4; ++nj)
        acc[mi][nj] = __builtin_amdgcn_mfma_f32_16x16x32_bf16(af[mi], bf[nj], acc[mi][nj], 0, 0, 0);
    __builtin_amdgcn_s_setprio(0);

    // ---- K-tile boundary: tile kt+1 resident + own reads drained ----
    if (st)                asm volatile("s_waitcnt vmcnt(6) lgkmcnt(0)" ::: "memory");
    else if (kt + 1 < nt)  asm volatile("s_waitcnt vmcnt(0) lgkmcnt(0)" ::: "memory");
    else                   asm volatile("s_waitcnt lgkmcnt(0)" ::: "memory");
    __builtin_amdgcn_s_barrier();
    cb = (cb + 1 == 3) ? 0 : cb + 1;
    fb = (fb + 1 == 3) ? 0 : fb + 1;
  }

  __syncthreads();   // drain before LDS reuse for epilogue

  // ---- epilogue via per-wave LDS tiles (two 64x64 parts, pitch 72 shorts) ----
  unsigned short* et = (unsigned short*)(smem + w * 9216);
  const int r4 = g << 2;
  const int nbase = n0 + wn * 64;
  const int seg = (OUTMODE == 1) ? (nbase >> 10) : 0;
  const int erow = lane >> 3, echunk = lane & 7;
  float bv[4];
  #pragma unroll
  for (int nj = 0; nj < 4; ++nj) bv[nj] = bias[nbase + nj * 16 + rA];

  #pragma unroll
  for (int p = 0; p < 2; ++p) {
    #pragma unroll
    for (int nj = 0; nj < 4; ++nj) {
      #pragma unroll
      for (int mi2 = 0; mi2 < 4; ++mi2) {
        #pragma unroll
        for (int j = 0; j < 4; ++j) {
          float x = acc[p * 4 + mi2][nj][j] + bv[nj];
          if (EPI == 1) x = gelu_f(x);
          const int mrl = mi2 * 16 + r4 + j;
          const int ncl = nj * 16 + rA;
          if (OUTMODE == 0 || seg < 2) et[mrl * 72 + ncl] = f2bf(x);
          else                         et[ncl * 72 + mrl] = f2bf(x);
        }
      }
    }
    const long mrow0 = m0 + wm * 128 + p * 64;
    if (OUTMODE == 0) {
      #pragma unroll
      for (int rr = 0; rr < 8; ++rr) {
        const int row = rr * 8 + erow;
        s16x8 v = *(const s16x8*)(et + row * 72 + echunk * 8);
        *(s16x8*)(C + (mrow0 + row) * N + nbase + echunk * 8) = v;
      }
    } else {
      const int nseg = nbase & 1023;
      if (seg < 2) {
        unsigned short* dst = C + (long)seg * 8388608;
        #pragma unroll
        for (int rr = 0; rr < 8; ++rr) {
          const int row = rr * 8 + erow;
          s16x8 v = *(const s16x8*)(et + row * 72 + echunk * 8);
          *(s16x8*)(dst + (mrow0 + row) * 1024 + nseg + echunk * 8) = v;
        }
      } else {
        unsigned short* vtp = C + 16777216;
        const int bb = (int)(mrow0 >> 10);
        const int ltok0 = (int)(mrow0 & 1023);
        #pragma unroll
        for (int rr = 0; rr < 8; ++rr) {
          const int nrow = rr * 8 + erow;
          s16x8 v = *(const s16x8*)(et + nrow * 72 + echunk * 8);
          *(s16x8*)(vtp + ((long)(bb * 1024 + nseg + nrow)) * 1024 + ltok0 + echunk * 8) = v;
        }
      }
    }
  }
}

// ---------------- flash attention v3 ----------------
__global__ __launch_bounds__(256) void flash_k(
    const unsigned short* __restrict__ q, const unsigned short* __restrict__ k,
    const unsigned short* __restrict__ vt, unsigned short* __restrict__ ctx)
{
  __shared__ unsigned short K2[2][64 * 128];  // 2x16KB, [kv][hd] rows 256B, chunk^=(row&7)
  __shared__ unsigned short Vs[128 * 64];     // 16KB, [hd][kv] rows 128B, chunk^=(row&7)
  __shared__ unsigned short Ps[4][32 * 72];   // per-wave P [32 q][64 kv], pitch 72
  const int L = blockIdx.x;
  const int qt = L >> 6;
  const int hb = (((L >> 3) & 7) << 3) + (L & 7);
  const int h = hb & 7, b = hb >> 3;
  const int tid = threadIdx.x, lane = tid & 63, w = tid >> 6;
  const int rA = lane & 15, g = lane >> 4;
  const int q0w = qt * 128 + w * 32;

  s16x8 qf[2][4];
  #pragma unroll
  for (int qi = 0; qi < 2; ++qi) {
    const unsigned short* qp = q + ((long)(b * Ln + q0w + qi * 16 + rA)) * Hn + h * HDn + g * 8;
    #pragma unroll
    for (int kk = 0; kk < 4; ++kk) qf[qi][kk] = *(const s16x8*)(qp + kk * 32);
  }
  asm volatile("s_waitcnt vmcnt(0)" ::: "memory");   // drain Q: vmcnt now counts only gload16

  f32x4 o[2][8];
  const f32x4 zero = {0.f, 0.f, 0.f, 0.f};
  #pragma unroll
  for (int qi = 0; qi < 2; ++qi)
    #pragma unroll
    for (int nn = 0; nn < 8; ++nn) o[qi][nn] = zero;
  float lrun[2][4];
  #pragma unroll
  for (int qi = 0; qi < 2; ++qi)
    #pragma unroll
    for (int j = 0; j < 4; ++j) lrun[qi][j] = 0.f;
  float m = 0.f;

  const float sc2 = 0.08838834764831845f * 1.4426950408889634f;  // 1/sqrt(128)*log2(e)

  const int krow0 = w * 16 + g;
  const int kc = lane & 15;
  const int vrow0 = w * 32 + (lane >> 3);
  const int vc = lane & 7;

  const unsigned short* kp[4];
  const unsigned short* vp[4];
  #pragma unroll
  for (int qq = 0; qq < 4; ++qq) {
    const int rk = krow0 + qq * 4;
    kp[qq] = k + ((long)(b * Ln + rk)) * Hn + h * HDn + ((kc ^ (rk & 7)) * 8);
    const int rv = vrow0 + qq * 8;
    vp[qq] = vt + ((long)(b * 1024 + h * HDn + rv)) * Ln + ((vc ^ (rv & 7)) * 8);
  }

  auto issueK = [&](int buf) {
    #pragma unroll
    for (int qq = 0; qq < 4; ++qq) {
      gload16(kp[qq], (char*)K2[buf] + w * 4096 + qq * 1024);
      kp[qq] += 64 * Hn;
    }
  };
  auto issueV = [&]() {
    #pragma unroll
    for (int qq = 0; qq < 4; ++qq) {
      gload16(vp[qq], (char*)Vs + w * 4096 + qq * 1024);
      vp[qq] += 64;
    }
  };

  issueK(0);
  asm volatile("s_waitcnt vmcnt(0)" ::: "memory");
  __builtin_amdgcn_s_barrier();

  for (int kvt = 0; kvt < 16; ++kvt) {
    const bool st = (kvt + 1 < 16);
    const char* Kcur = (const char*)K2[kvt & 1];
    issueV();
    if (st) issueK((kvt + 1) & 1);

    f32x4 sacc[2][4];
    #pragma unroll
    for (int qi = 0; qi < 2; ++qi)
      #pragma unroll
      for (int nj = 0; nj < 4; ++nj) sacc[qi][nj] = zero;
    __builtin_amdgcn_s_setprio(1);
    #pragma unroll
    for (int kk = 0; kk < 4; ++kk) {
      #pragma unroll
      for (int nj = 0; nj < 4; ++nj) {
        const int row = nj * 16 + rA;
        const int byt = row * 256 + (((kk * 4 + g) ^ (row & 7)) << 4);
        s16x8 kf = *(const s16x8*)(Kcur + byt);
        sacc[0][nj] = __builtin_amdgcn_mfma_f32_16x16x32_bf16(qf[0][kk], kf, sacc[0][nj], 0, 0, 0);
        sacc[1][nj] = __builtin_amdgcn_mfma_f32_16x16x32_bf16(qf[1][kk], kf, sacc[1][nj], 0, 0, 0);
      }
    }
    __builtin_amdgcn_s_setprio(0);

    float t8[8];
    #pragma unroll
    for (int qi = 0; qi < 2; ++qi)
      #pragma unroll
      for (int nj = 0; nj < 4; ++nj) {
        float s0 = sacc[qi][nj][0] * sc2;
        float s1 = sacc[qi][nj][1] * sc2;
        float s2 = sacc[qi][nj][2] * sc2;
        float s3 = sacc[qi][nj][3] * sc2;
        sacc[qi][nj][0] = s0; sacc[qi][nj][1] = s1;
        sacc[qi][nj][2] = s2; sacc[qi][nj][3] = s3;
        t8[qi * 4 + nj] = fmaxf(fmaxf(s0, s1), fmaxf(s2, s3));
      }
    const float vmax = fmaxf(fmaxf(fmaxf(t8[0], t8[1]), fmaxf(t8[2], t8[3])),
                             fmaxf(fmaxf(t8[4], t8[5]), fmaxf(t8[6], t8[7])));
    if (!__all(vmax <= m + 8.0f)) {
      float mn = vmax;
      #pragma unroll
      for (int mm = 1; mm < 64; mm <<= 1) mn = fmaxf(mn, __shfl_xor(mn, mm, 64));
      const float al = exp2f(m - mn);
      #pragma unroll
      for (int qi = 0; qi < 2; ++qi) {
        #pragma unroll
        for (int nn = 0; nn < 8; ++nn)
          #pragma unroll
          for (int j = 0; j < 4; ++j) o[qi][nn][j] *= al;
        #pragma unroll
        for (int j = 0; j < 4; ++j) lrun[qi][j] *= al;
      }
      m = mn;
    }

    #pragma unroll
    for (int qi = 0; qi < 2; ++qi)
      #pragma unroll
      for (int j = 0; j < 4; ++j) {
        float p0 = exp2f(sacc[qi][0][j] - m);
        float p1 = exp2f(sacc[qi][1][j] - m);
        float p2 = exp2f(sacc[qi][2][j] - m);
        float p3 = exp2f(sacc[qi][3][j] - m);
        lrun[qi][j] += (p0 + p1) + (p2 + p3);
        const int prow = (qi * 16 + g * 4 + j) * 72;
        Ps[w][prow + 0 * 16 + rA] = f2bf(p0);
        Ps[w][prow + 1 * 16 + rA] = f2bf(p1);
        Ps[w][prow + 2 * 16 + rA] = f2bf(p2);
        Ps[w][prow + 3 * 16 + rA] = f2bf(p3);
      }

    if (st) asm volatile("s_waitcnt vmcnt(4)" ::: "memory");
    else    asm volatile("s_waitcnt vmcnt(0)" ::: "memory");
    __builtin_amdgcn_s_barrier();

    s16x8 pf[2][2];
    #pragma unroll
    for (int qi = 0; qi < 2; ++qi)
      #pragma unroll
      for (int kk2 = 0; kk2 < 2; ++kk2)
        pf[qi][kk2] = *(const s16x8*)(&Ps[w][(qi * 16 + rA) * 72 + kk2 * 32 + g * 8]);
    __builtin_amdgcn_s_setprio(1);
    #pragma unroll
    for (int kk2 = 0; kk2 < 2; ++kk2) {
      #pragma unroll
      for (int nn = 0; nn < 8; ++nn) {
        const int row = nn * 16 + rA;
        const int byt = row * 128 + (((kk2 * 4 + g) ^ (row & 7)) << 4);
        s16x8 vf = *(const s16x8*)((const char*)Vs + byt);
        o[0][nn] = __builtin_amdgcn_mfma_f32_16x16x32_bf16(pf[0][kk2], vf, o[0][nn], 0, 0, 0);
        o[1][nn] = __builtin_amdgcn_mfma_f32_16x16x32_bf16(pf[1][kk2], vf, o[1][nn], 0, 0, 0);
      }
    }
    __builtin_amdgcn_s_setprio(0);

    if (st) asm volatile("s_waitcnt vmcnt(0) lgkmcnt(0)" ::: "memory");
    else    asm volatile("s_waitcnt lgkmcnt(0)" ::: "memory");
    __builtin_amdgcn_s_barrier();
  }

  float linv[2][4];
  #pragma unroll
  for (int qi = 0; qi < 2; ++qi)
    #pragma unroll
    for (int j = 0; j < 4; ++j) {
      float l = lrun[qi][j];
      #pragma unroll
      for (int mm = 1; mm < 16; mm <<= 1) l += __shfl_xor(l, mm, 64);
      linv[qi][j] = 1.0f / l;
    }
  #pragma unroll
  for (int qi = 0; qi < 2; ++qi)
    #pragma unroll
    for (int nn = 0; nn < 8; ++nn)
      #pragma unroll
      for (int j = 0; j < 4; ++j) {
        const int row = q0w + qi * 16 + g * 4 + j;
        ctx[((long)(b * Ln + row)) * Hn + h * HDn + nn * 16 + rA] = f2bf(o[qi][nn][j] * linv[qi][j]);
      }
}

// ---------------- diversity ----------------
__global__ __launch_bounds__(256) void div_part_k(const unsigned short* __restrict__ br, float* __restrict__ part)
{
  const int b = blockIdx.y, ch = blockIdx.x;
  const unsigned short* a = br + (long)b * (2L * Sn * Hn);
  const unsigned short* c = a + (long)Sn * Hn;
  const int base = ch * 16384 + threadIdx.x * 8;
  float dot = 0.f, na = 0.f, nb = 0.f;
  #pragma unroll
  for (int i = 0; i < 8; ++i) {
    const int idx = base + i * 2048;
    s16x8 av = *(const s16x8*)(a + idx);
    s16x8 cv = *(const s16x8*)(c + idx);
    #pragma unroll
    for (int e = 0; e < 8; ++e) {
      float fa = bf2f((unsigned short)av[e]);
      float fc = bf2f((unsigned short)cv[e]);
      dot += fa * fc; na += fa * fa; nb += fc * fc;
    }
  }
  #pragma unroll
  for (int mm = 1; mm < 64; mm <<= 1) {
    dot += __shfl_xor(dot, mm, 64);
    na  += __shfl_xor(na, mm, 64);
    nb  += __shfl_xor(nb, mm, 64);
  }
  __shared__ float red[12];
  const int lane = threadIdx.x & 63, w = threadIdx.x >> 6;
  if (lane == 0) { red[w * 3] = dot; red[w * 3 + 1] = na; red[w * 3 + 2] = nb; }
  __syncthreads();
  if (threadIdx.x == 0) {
    float d = 0, x = 0, y = 0;
    for (int i = 0; i < 4; ++i) { d += red[i * 3]; x += red[i * 3 + 1]; y += red[i * 3 + 2]; }
    float* op = part + ((long)(b * 32 + ch)) * 3;
    op[0] = d; op[1] = x; op[2] = y;
  }
}

__global__ __launch_bounds__(64) void div_final_k(const float* __restrict__ part, float* __restrict__ outp)
{
  __shared__ float cosr[8];
  const int tid = threadIdx.x;
  if (tid < 8) {
    float d = 0, x = 0, y = 0;
    for (int i = 0; i < 32; ++i) {
      const float* p = part + ((long)(tid * 32 + i)) * 3;
      d += p[0]; x += p[1]; y += p[2];
    }
    cosr[tid] = d / fmaxf(sqrtf(x) * sqrtf(y), 1e-8f);
  }
  __syncthreads();
  if (tid == 0) {
    float s = 0.f;
    for (int i = 0; i < 8; ++i) s += 1.f - cosr[i];
    outp[0] = s * (1.f / 8.f);
  }
}

// ---------------- weighted combine ----------------
__global__ __launch_bounds__(256) void combine_k(const unsigned short* __restrict__ att,
                                                 const float* __restrict__ wts, float* __restrict__ out)
{
  const long i = ((long)blockIdx.x * 256 + threadIdx.x) * 8;
  const int b = (int)(i >> 19);           // S*H = 524288
  const long rem = i & 524287;
  const unsigned short* a0 = att + (long)b * (2L * Sn * Hn) + rem;
  const unsigned short* a1 = a0 + (long)Sn * Hn;
  const float w0 = wts[b * 2], w1 = wts[b * 2 + 1];
  s16x8 v0 = *(const s16x8*)a0;
  s16x8 v1 = *(const s16x8*)a1;
  float r[8];
  #pragma unroll
  for (int e = 0; e < 8; ++e) r[e] = w0 * bf2f((unsigned short)v0[e]) + w1 * bf2f((unsigned short)v1[e]);
  *(float4*)(out + i)     = make_float4(r[0], r[1], r[2], r[3]);
  *(float4*)(out + i + 4) = make_float4(r[4], r[5], r[6], r[7]);
}

// ---------------- launch ----------------
extern "C" void kernel_launch(void* const* d_in, const int* in_sizes, int n_in,
                              void* d_out, int out_size, void* d_ws, size_t ws_size,
                              hipStream_t stream)
{
  (void)in_sizes; (void)n_in; (void)out_size; (void)ws_size;
  const float* hidden   = (const float*)d_in[0];
  const float* router_w = (const float*)d_in[1];
  const float* router_b = (const float*)d_in[2];
  const float* W1 = (const float*)d_in[3];
  const float* b1 = (const float*)d_in[4];
  const float* W2 = (const float*)d_in[5];
  const float* b2 = (const float*)d_in[6];
  const float* Wq = (const float*)d_in[7];
  const float* bq = (const float*)d_in[8];
  const float* Wk = (const float*)d_in[9];
  const float* bk = (const float*)d_in[10];
  const float* Wv = (const float*)d_in[11];
  const float* bv = (const float*)d_in[12];
  const float* Wo = (const float*)d_in[13];
  const float* bo = (const float*)d_in[14];
  float* out = (float*)d_out;

  char* ws = (char*)d_ws;
  float* pooled  = (float*)(ws);
  float* probs   = (float*)(ws + 163840);
  int*   topi    = (int*)  (ws + 164096);
  float* wts     = (float*)(ws + 164352);
  int*   flags   = (int*)  (ws + 164608);
  float* dpart   = (float*)(ws + 164864);
  float* qkvbias = (float*)(ws + 167936);
  unsigned short* hid_bf = (unsigned short*)(ws + 262144);                           // 8.39MB
  unsigned short* Wt     = (unsigned short*)(ws + 262144 + 8388608);                 // 67.1MB
  unsigned short* hbuf   = (unsigned short*)(ws + 262144 + 8388608 + 67108864);      // 67.1MB
  unsigned short* br     = (unsigned short*)(ws + 262144 + 8388608 + 134217728);     // 16.8MB
  unsigned short* wqkvo  = (unsigned short*)(ws + 262144 + 8388608 + 134217728 + 16777216); // 8.4MB
  unsigned short* qb  = Wt;
  unsigned short* kbf = Wt + 8388608;
  unsigned short* vt  = Wt + 16777216;
  unsigned short* ctx = hbuf;
  unsigned short* att = hbuf + 8388608;
  unsigned short* wqt = wqkvo;
  unsigned short* wkt = wqkvo + 1048576;
  unsigned short* wvt = wqkvo + 2097152;
  unsigned short* wot = wqkvo + 3145728;
  // ppart (32*8*1024 f32 = 1MB) aliases the Wt region: pool/router complete
  // before the W1 transpose writes Wt (single stream, serialized).
  float* ppart = (float*)Wt;

  // 1. fused convert+pool partials (reads f32 hidden once)
  poolcvt_k<<<dim3(Bn, 32), 256, 0, stream>>>(hidden, hid_bf, ppart);
  pool_final_k<<<dim3(32), 256, 0, stream>>>(ppart, pooled);
  router_k<<<1, 256, 0, stream>>>(pooled, router_w, router_b, probs, topi, wts, flags, out + OUT_COMBINED);

  // 2. weight transposes
  bias3_k<<<4, 256, 0, stream>>>(bq, bk, bv, qkvbias);
  transpose_k<<<dim3(64, 16, Tn), 256, 0, stream>>>(W1, Wt, Hn, FFn, (long)Hn * FFn, (long)FFn * Hn, flags);
  transpose_k<<<dim3(16, 16, 1), 256, 0, stream>>>(Wq, wqt, Hn, Hn, 0, 0, nullptr);
  transpose_k<<<dim3(16, 16, 1), 256, 0, stream>>>(Wk, wkt, Hn, Hn, 0, 0, nullptr);
  transpose_k<<<dim3(16, 16, 1), 256, 0, stream>>>(Wv, wvt, Hn, Hn, 0, 0, nullptr);
  transpose_k<<<dim3(16, 16, 1), 256, 0, stream>>>(Wo, wot, Hn, Hn, 0, 0, nullptr);

  // 3. FFN1 (gelu): grid (32,2,16) = 1024 blocks
  gemmT_k<1, 0><<<dim3(FFn / 128, Sn / 256, 16), 256, 0, stream>>>(
      hid_bf, Wt, b1, hbuf, FFn, Hn, topi, 2,
      (long)Sn * Hn, 0L, (long)FFn * Hn, FFn, (long)Sn * FFn);

  // 4. W2 transpose reuses Wt region (W1t dead)
  transpose_k<<<dim3(16, 64, Tn), 256, 0, stream>>>(W2, Wt, FFn, Hn, (long)FFn * Hn, (long)Hn * FFn, flags);

  // 5. FFN2: grid (8,2,16) = 256 blocks
  gemmT_k<0, 0><<<dim3(Hn / 128, Sn / 256, 16), 256, 0, stream>>>(
      hbuf, Wt, b2, br, Hn, FFn, topi, 2,
      0L, (long)Sn * FFn, (long)Hn * FFn, Hn, (long)Sn * Hn);

  // 6. diversity from branch_out
  div_part_k<<<dim3(32, Bn), 256, 0, stream>>>(br, dpart);
  div_final_k<<<1, 64, 0, stream>>>(dpart, out + OUT_COMBINED + 1);

  // 7. fused QKV projection: grid (24,32) = 768 blocks
  gemmT_k<0, 1><<<dim3(3072 / 128, (Bn * Ln) / 256, 1), 256, 0, stream>>>(
      br, wqkvo, qkvbias, qb, 3072, Hn, nullptr, 0, 0L, 0L, 0L, 0, 0L);

  // 8. flash attention v3 (1-D grid, XCD-locality remap)
  flash_k<<<dim3(512), 256, 0, stream>>>(qb, kbf, vt, ctx);

  // 9. output projection: grid (8,32) = 256 blocks
  gemmT_k<0, 0><<<dim3(Hn / 128, (Bn * Ln) / 256, 1), 256, 0, stream>>>(
      ctx, wot, bo, att, Hn, Hn, nullptr, 0, 0L, 0L, 0L, 0, 0L);

  // 10. weighted combine -> f32 output
  combine_k<<<2048, 256, 0, stream>>>(att, wts, out);
}

// Round 13
// 491.584 us; speedup vs baseline: 1.3311x; 1.0254x over previous
//
#include <hip/hip_runtime.h>
#include <hip/hip_bf16.h>
#include <math.h>

typedef float f32x4 __attribute__((ext_vector_type(4)));
typedef short s16x8 __attribute__((ext_vector_type(8)));
typedef short s16x4 __attribute__((ext_vector_type(4)));
typedef unsigned int u32;

#define DEVI __device__ __forceinline__

// ---- sizes ----
#define Bn   8
#define Sn   512
#define Hn   1024
#define Tn   8
#define Kn   2
#define FFn  4096
#define NHn  8
#define HDn  128
#define Ln   1024            // K*S
#define OUT_COMBINED 4194304 // B*S*H

DEVI unsigned short f2bf(float x) {
  __hip_bfloat16 h = __float2bfloat16(x);
  union { __hip_bfloat16 h; unsigned short u; } cv; cv.h = h; return cv.u;
}
DEVI float bf2f(unsigned short u) {
  union { u32 i; float f; } cv; cv.i = ((u32)u) << 16; return cv.f;
}
// tanh-form GELU: |err| vs exact erf-GELU < 1e-3 (bf16 eps dominates)
DEVI float gelu_f(float x) {
  float t = x * x * x;
  float y = 0.7978845608028654f * x + 0.03567740813f * t;
  float e = exp2f(2.8853900817779268f * y);      // e^{2y}
  return x - x / (e + 1.0f);                      // x * e/(e+1)
}

typedef __attribute__((address_space(3))) u32 lds_u32;
typedef __attribute__((address_space(1))) u32 glb_u32;
DEVI void gload16(const void* g, void* l) {
  __builtin_amdgcn_global_load_lds((const glb_u32*)g, (lds_u32*)l, 16, 0, 0);
}

// ---------------- fused f32->bf16 convert + pool partials ----------------
__global__ __launch_bounds__(256) void poolcvt_k(const float* __restrict__ hid,
                                                 unsigned short* __restrict__ hbf,
                                                 float* __restrict__ part)
{
  const int b = blockIdx.x, scn = blockIdx.y;
  const int hh = threadIdx.x * 4;
  float4 acc = make_float4(0.f, 0.f, 0.f, 0.f);
  const long base = ((long)b * Sn + (long)scn * 16) * Hn + hh;
  for (int s = 0; s < 16; ++s) {
    float4 v = *(const float4*)(hid + base + (long)s * Hn);
    s16x4 o;
    o[0] = (short)f2bf(v.x); o[1] = (short)f2bf(v.y);
    o[2] = (short)f2bf(v.z); o[3] = (short)f2bf(v.w);
    *(s16x4*)(hbf + base + (long)s * Hn) = o;
    acc.x += v.x; acc.y += v.y; acc.z += v.z; acc.w += v.w;
  }
  *(float4*)(part + ((long)(scn * Bn + b)) * Hn + hh) = acc;
}

__global__ __launch_bounds__(256) void pool_final_k(const float* __restrict__ part, float* __restrict__ pooled)
{
  const int i = blockIdx.x * 256 + threadIdx.x;
  float s = 0.f;
  for (int sc = 0; sc < 32; ++sc) s += part[sc * (Bn * Hn) + i];
  pooled[i] = s * (1.f / (float)Sn);
}

// ---------------- router + entropy (parallel dot: 256 threads) ----------------
__global__ __launch_bounds__(256) void router_k(
    const float* __restrict__ pooled, const float* __restrict__ rw, const float* __restrict__ rb,
    float* __restrict__ probs, int* __restrict__ topi, float* __restrict__ wts,
    int* __restrict__ flags, float* __restrict__ entropy_out)
{
  __shared__ float partial[256];
  __shared__ float lg[64];
  __shared__ int sfl[8];
  __shared__ float sent[8];
  const int tid = threadIdx.x;
  const int bt = tid & 63, slice = tid >> 6;
  const int b = bt >> 3, t = bt & 7;
  if (tid < 8) sfl[tid] = 0;
  float acc = 0.f;
  const float* pb = pooled + b * Hn;
  for (int i = slice * 256; i < slice * 256 + 256; ++i) acc += pb[i] * rw[i * Tn + t];
  partial[tid] = acc;
  __syncthreads();
  if (tid < 64) lg[tid] = rb[t] + partial[tid] + partial[tid + 64] + partial[tid + 128] + partial[tid + 192];
  __syncthreads();
  if (tid < 64 && t == 0) {
    float p[8];
    float mx = lg[b * 8];
    for (int i = 1; i < 8; ++i) mx = fmaxf(mx, lg[b * 8 + i]);
    float ssum = 0.f;
    for (int i = 0; i < 8; ++i) { p[i] = expf(lg[b * 8 + i] - mx); ssum += p[i]; }
    float ent = 0.f;
    for (int i = 0; i < 8; ++i) { p[i] /= ssum; ent -= p[i] * logf(p[i] + 1e-8f); probs[b * 8 + i] = p[i]; }
    sent[b] = ent;
    int i1 = 0;
    for (int i = 1; i < 8; ++i) if (p[i] > p[i1]) i1 = i;   // strict > : lowest index on ties (lax.top_k)
    int i2 = (i1 == 0) ? 1 : 0;
    for (int i = 0; i < 8; ++i) if (i != i1 && p[i] > p[i2]) i2 = i;
    float w0 = 1.f / (1.f + expf(p[i2] - p[i1]));
    float w1 = 1.f / (1.f + expf(p[i1] - p[i2]));
    topi[b * 2] = i1; topi[b * 2 + 1] = i2;
    wts[b * 2] = w0; wts[b * 2 + 1] = w1;
    atomicOr(&sfl[i1], 1); atomicOr(&sfl[i2], 1);
  }
  __syncthreads();
  if (tid < 8) flags[tid] = sfl[tid];
  if (tid == 0) {
    float e = 0.f;
    for (int i = 0; i < 8; ++i) e += sent[i];
    entropy_out[0] = e * (1.f / (float)Bn);
  }
}

// ---------------- bias concat for fused QKV ----------------
__global__ __launch_bounds__(256) void bias3_k(const float* __restrict__ bq, const float* __restrict__ bk,
                                               const float* __restrict__ bv, float* __restrict__ o)
{
  const int i = blockIdx.x * 256 + threadIdx.x;   // 0..1023
  o[i] = bq[i]; o[i + 1024] = bk[i]; o[i + 2048] = bv[i];
}

// ---------------- transpose+convert: in f32 [Kd][N] -> out bf16 [N][Kd], 64x64 tiles ----------------
__global__ __launch_bounds__(256) void transpose_k(const float* __restrict__ Win, unsigned short* __restrict__ Wout,
                                                   int Kd, int N, long sIn, long sOut, const int* __restrict__ flags)
{
  const int t = blockIdx.z;
  if (flags && flags[t] == 0) return;   // uniform per block
  __shared__ float tile[64][65];
  const float* in = Win + (long)t * sIn;
  unsigned short* out = Wout + (long)t * sOut;
  const int kb = blockIdx.y * 64, nb = blockIdx.x * 64;
  const int tx = threadIdx.x & 15, ty = threadIdx.x >> 4;
  #pragma unroll
  for (int i = 0; i < 4; ++i) {
    const int r = ty + i * 16;
    float4 v = *(const float4*)(in + (long)(kb + r) * N + nb + tx * 4);
    tile[r][tx * 4 + 0] = v.x; tile[r][tx * 4 + 1] = v.y;
    tile[r][tx * 4 + 2] = v.z; tile[r][tx * 4 + 3] = v.w;
  }
  __syncthreads();
  #pragma unroll
  for (int i = 0; i < 4; ++i) {
    const int n = ty + i * 16;
    s16x4 o;
    #pragma unroll
    for (int j = 0; j < 4; ++j) o[j] = (short)f2bf(tile[tx * 4 + j][n]);
    *(s16x4*)(out + (long)(nb + n) * Kd + kb + tx * 4) = o;
  }
}

// ---------------- 4x fused H*H transpose (Wq,Wk,Wv,Wo -> wqkvo), z selects ----------------
__global__ __launch_bounds__(256) void transpose4_k(const float* __restrict__ w0, const float* __restrict__ w1,
                                                    const float* __restrict__ w2, const float* __restrict__ w3,
                                                    unsigned short* __restrict__ dst)
{
  __shared__ float tile[64][65];
  const int z = blockIdx.z;
  const float* in = (z == 0) ? w0 : (z == 1) ? w1 : (z == 2) ? w2 : w3;
  unsigned short* out = dst + (long)z * 1048576;
  const int kb = blockIdx.y * 64, nb = blockIdx.x * 64;
  const int tx = threadIdx.x & 15, ty = threadIdx.x >> 4;
  #pragma unroll
  for (int i = 0; i < 4; ++i) {
    const int r = ty + i * 16;
    float4 v = *(const float4*)(in + (long)(kb + r) * Hn + nb + tx * 4);
    tile[r][tx * 4 + 0] = v.x; tile[r][tx * 4 + 1] = v.y;
    tile[r][tx * 4 + 2] = v.z; tile[r][tx * 4 + 3] = v.w;
  }
  __syncthreads();
  #pragma unroll
  for (int i = 0; i < 4; ++i) {
    const int n = ty + i * 16;
    s16x4 o;
    #pragma unroll
    for (int j = 0; j < 4; ++j) o[j] = (short)f2bf(tile[tx * 4 + j][n]);
    *(s16x4*)(out + (long)(nb + n) * Hn + kb + tx * 4) = o;
  }
}

// ---------------- GEMM: C[M,N] = A[M,Kd] @ Bt[N,Kd]^T + bias ----------------
// BM=256, BN=128, BK=32. 4 waves (2M x 2N), wave tile 128x64. NBUF=3 (72KB LDS)
// -> 2 blocks/CU. SINGLE barrier per K-tile; counted boundary vmcnt(6)+lgkmcnt(0).
// Swizzle: chunk ^= (row>>1)&3 via pre-swizzled GLOBAL source (LDS dest linear).
// T1 bijective XCD remap. EPI 1 = tanh-GELU.
// OUTMODE 0: normal. OUTMODE 1: fused QKV (q/k normal, v transposed).
// OUTMODE 2: fused outproj+combine -- M-tile = (b, s-range) pair of thought rows
//   (tile rows 0-127 = k0, 128-255 = k1); epilogue combines via cross-wave LDS
//   and writes f32 `outp` directly (att buffer + combine kernel eliminated).
template<int EPI, int OUTMODE>
__global__ __launch_bounds__(256, 2) void gemmT_k(
    const unsigned short* __restrict__ A0, const unsigned short* __restrict__ Bt0,
    const float* __restrict__ bias0, unsigned short* __restrict__ C0,
    int N, int Kd,
    const int* __restrict__ topi, int kTop,
    long sA_b, long sA_p, long sBt_t, int sBias_t, long sC_p,
    const float* __restrict__ wts2, float* __restrict__ outp)
{
  __shared__ __align__(16) char smem[73728];
  char* const Ab = smem;              // 3 x 16384 (256 rows x 64B)
  char* const Bb = smem + 49152;      // 3 x  8192 (128 rows x 64B)

  // ---- T1 bijective XCD tile remap ----
  const int gx = gridDim.x, gy = gridDim.y;
  const int nwg = gx * gy * gridDim.z;
  const int hw = blockIdx.x + gx * (blockIdx.y + gy * blockIdx.z);
  const int q = nwg >> 3, r = nwg & 7;
  const int xcd = hw & 7, sub = hw >> 3;
  int lin = (xcd < r ? xcd * (q + 1) : r * (q + 1) + (xcd - r) * q) + sub;
  const int bx = lin % gx; lin /= gx;
  const int by = lin % gy;
  const int bz = lin / gy;

  const int bidx = kTop ? (bz / kTop) : 0;
  const int te = topi ? topi[bz] : 0;
  const unsigned short* A = A0 + (long)bidx * sA_b + (long)bz * sA_p;
  const unsigned short* Bt = Bt0 + (long)te * sBt_t;
  const float* bias = bias0 + (long)te * sBias_t;
  unsigned short* C = C0 + (long)bz * sC_p;

  const int m0 = by * 256;
  const int n0 = bx * 128;
  const int tid = threadIdx.x;
  const int lane = tid & 63, w = tid >> 6;
  const int wm = w >> 1, wn = w & 1;
  const int rA = lane & 15, g = lane >> 4;
  // OUTMODE 2: by -> (b2, s0b); tile rows 0-127 = (b2, k0, s0b..), 128-255 = k1
  const int b2 = by >> 2, s0b = (by & 3) * 128;

  // ---- staging sources (pre-swizzled global chunk, f(r) = (r>>1)&3) ----
  const int sr = lane >> 2;                 // 0..15 (row within 16-row issue block)
  const int sc = lane & 3;                  // chunk
  const int csw = (sc ^ ((sr >> 1) & 3)) * 8;   // bf16-elem offset
  const unsigned short* gAw;
  if (OUTMODE == 2)
    gAw = A + (long)(b2 * 1024 + (w >> 1) * 512 + s0b + (w & 1) * 64 + sr) * Kd + csw;
  else
    gAw = A + (long)(m0 + w * 64 + sr) * Kd + csw;  // + i*16*Kd + kt*32
  const unsigned short* gBw = Bt + (long)(n0 + w * 32 + sr) * Kd + csw;
  const int ldso = lane << 4;

  // ---- fragment LDS byte offsets (swizzled read, same f) ----
  const int sl = (rA >> 1) & 3;
  int aoff[8], boff[4];
  #pragma unroll
  for (int mi = 0; mi < 8; ++mi)
    aoff[mi] = (wm * 128 + mi * 16 + rA) * 64 + ((g ^ sl) << 4);
  #pragma unroll
  for (int nj = 0; nj < 4; ++nj)
    boff[nj] = (wn * 64 + nj * 16 + rA) * 64 + ((g ^ sl) << 4);

  f32x4 acc[8][4];
  const f32x4 zero = {0.f, 0.f, 0.f, 0.f};
  #pragma unroll
  for (int i = 0; i < 8; ++i)
    #pragma unroll
    for (int j = 0; j < 4; ++j) acc[i][j] = zero;

  const int nt = Kd >> 5;

  auto stageA = [&](int kt2, int buf, int i) {
    gload16(gAw + (long)i * 16 * Kd + kt2 * 32, Ab + buf * 16384 + w * 4096 + i * 1024 + ldso);
  };
  auto stageB = [&](int kt2, int buf, int i) {
    gload16(gBw + (long)i * 16 * Kd + kt2 * 32, Bb + buf * 8192 + w * 2048 + i * 1024 + ldso);
  };

  // ---- prologue: stage tiles 0,1 (6 issues each, in order) ----
  #pragma unroll
  for (int j = 0; j < 2; ++j) {
    stageA(j, j, 0); stageA(j, j, 1); stageB(j, j, 0);
    stageA(j, j, 2); stageA(j, j, 3); stageB(j, j, 1);
  }
  asm volatile("s_waitcnt vmcnt(6)" ::: "memory");   // tile 0 landed
  __builtin_amdgcn_s_barrier();

  int cb = 0, fb = 2;
  for (int kt = 0; kt < nt; ++kt) {
    const char* pa = Ab + cb * 16384;
    const char* pb = Bb + cb * 8192;
    const bool st = (kt + 2 < nt);
    const int ft = kt + 2;

    // ---- issue all 12 fragment reads + 6 stage issues; no mid barrier ----
    s16x8 af[8], bf[4];
    #pragma unroll
    for (int mi = 0; mi < 4; ++mi) af[mi] = *(const s16x8*)(pa + aoff[mi]);
    #pragma unroll
    for (int nj = 0; nj < 4; ++nj) bf[nj] = *(const s16x8*)(pb + boff[nj]);
    if (st) { stageA(ft, fb, 0); stageA(ft, fb, 1); stageB(ft, fb, 0); }
    #pragma unroll
    for (int mi = 0; mi < 4; ++mi) af[4 + mi] = *(const s16x8*)(pa + aoff[4 + mi]);
    if (st) { stageA(ft, fb, 2); stageA(ft, fb, 3); stageB(ft, fb, 1); }

    // ---- 32 MFMA (compiler lgkmcnt interleaves remaining reads underneath) ----
    __builtin_amdgcn_s_setprio(1);
    #pragma unroll
    for (int mi = 0; mi < 8; ++mi)
      #pragma unroll
      for (int nj = 0; nj < 4; ++nj)
        acc[mi][nj] = __builtin_amdgcn_mfma_f32_16x16x32_bf16(af[mi], bf[nj], acc[mi][nj], 0, 0, 0);
    __builtin_amdgcn_s_setprio(0);

    // ---- K-tile boundary: tile kt+1 resident + own reads drained ----
    if (st)                asm volatile("s_waitcnt vmcnt(6) lgkmcnt(0)" ::: "memory");
    else if (kt + 1 < nt)  asm volatile("s_waitcnt vmcnt(0) lgkmcnt(0)" ::: "memory");
    else                   asm volatile("s_waitcnt lgkmcnt(0)" ::: "memory");
    __builtin_amdgcn_s_barrier();
    cb = (cb + 1 == 3) ? 0 : cb + 1;
    fb = (fb + 1 == 3) ? 0 : fb + 1;
  }

  __syncthreads();   // drain before LDS reuse for epilogue

  // ---- epilogue via per-wave LDS tiles (two 64x64 parts, pitch 72 shorts) ----
  unsigned short* et = (unsigned short*)(smem + w * 9216);
  const int r4 = g << 2;
  const int nbase = n0 + wn * 64;
  const int seg = (OUTMODE == 1) ? (nbase >> 10) : 0;
  const int erow = lane >> 3, echunk = lane & 7;
  float bv[4];
  #pragma unroll
  for (int nj = 0; nj < 4; ++nj) bv[nj] = bias[nbase + nj * 16 + rA];

  #pragma unroll
  for (int p = 0; p < 2; ++p) {
    #pragma unroll
    for (int nj = 0; nj < 4; ++nj) {
      #pragma unroll
      for (int mi2 = 0; mi2 < 4; ++mi2) {
        #pragma unroll
        for (int j = 0; j < 4; ++j) {
          float x = acc[p * 4 + mi2][nj][j] + bv[nj];
          if (EPI == 1) x = gelu_f(x);
          const int mrl = mi2 * 16 + r4 + j;
          const int ncl = nj * 16 + rA;
          if (OUTMODE == 2 || OUTMODE == 0 || seg < 2) et[mrl * 72 + ncl] = f2bf(x);
          else                                         et[ncl * 72 + mrl] = f2bf(x);
        }
      }
    }
    const long mrow0 = m0 + wm * 128 + p * 64;
    if (OUTMODE == 0) {
      #pragma unroll
      for (int rr = 0; rr < 8; ++rr) {
        const int row = rr * 8 + erow;
        s16x8 v = *(const s16x8*)(et + row * 72 + echunk * 8);
        *(s16x8*)(C + (mrow0 + row) * N + nbase + echunk * 8) = v;
      }
    } else if (OUTMODE == 1) {
      const int nseg = nbase & 1023;
      if (seg < 2) {
        unsigned short* dst = C + (long)seg * 8388608;
        #pragma unroll
        for (int rr = 0; rr < 8; ++rr) {
          const int row = rr * 8 + erow;
          s16x8 v = *(const s16x8*)(et + row * 72 + echunk * 8);
          *(s16x8*)(dst + (mrow0 + row) * 1024 + nseg + echunk * 8) = v;
        }
      } else {
        unsigned short* vtp = C + 16777216;
        const int bb = (int)(mrow0 >> 10);
        const int ltok0 = (int)(mrow0 & 1023);
        #pragma unroll
        for (int rr = 0; rr < 8; ++rr) {
          const int nrow = rr * 8 + erow;
          s16x8 v = *(const s16x8*)(et + nrow * 72 + echunk * 8);
          *(s16x8*)(vtp + ((long)(bb * 1024 + nseg + nrow)) * 1024 + ltok0 + echunk * 8) = v;
        }
      }
    } else {
      // ---- OUTMODE 2: cross-wave combine (k0 in waves 0/1, k1 in waves 2/3) ----
      __syncthreads();   // all et tiles of this p written
      if (w < 2) {
        const unsigned short* e0 = (const unsigned short*)(smem + w * 9216);
        const unsigned short* e1 = (const unsigned short*)(smem + (w + 2) * 9216);
        const float w0v = wts2[b2 * 2], w1v = wts2[b2 * 2 + 1];
        const int nb2 = n0 + (w & 1) * 64;
        const long srow0 = (long)b2 * Sn + s0b + p * 64;
        #pragma unroll
        for (int rr = 0; rr < 8; ++rr) {
          const int row = rr * 8 + erow;
          s16x8 v0 = *(const s16x8*)(e0 + row * 72 + echunk * 8);
          s16x8 v1 = *(const s16x8*)(e1 + row * 72 + echunk * 8);
          float rv[8];
          #pragma unroll
          for (int e = 0; e < 8; ++e)
            rv[e] = w0v * bf2f((unsigned short)v0[e]) + w1v * bf2f((unsigned short)v1[e]);
          float* op = outp + (srow0 + row) * Hn + nb2 + echunk * 8;
          *(float4*)op       = make_float4(rv[0], rv[1], rv[2], rv[3]);
          *(float4*)(op + 4) = make_float4(rv[4], rv[5], rv[6], rv[7]);
        }
      }
      __syncthreads();   // et free for next p
    }
  }
}

// ---------------- flash attention v3 ----------------
__global__ __launch_bounds__(256) void flash_k(
    const unsigned short* __restrict__ q, const unsigned short* __restrict__ k,
    const unsigned short* __restrict__ vt, unsigned short* __restrict__ ctx)
{
  __shared__ unsigned short K2[2][64 * 128];  // 2x16KB, [kv][hd] rows 256B, chunk^=(row&7)
  __shared__ unsigned short Vs[128 * 64];     // 16KB, [hd][kv] rows 128B, chunk^=(row&7)
  __shared__ unsigned short Ps[4][32 * 72];   // per-wave P [32 q][64 kv], pitch 72
  const int L = blockIdx.x;
  const int qt = L >> 6;
  const int hb = (((L >> 3) & 7) << 3) + (L & 7);
  const int h = hb & 7, b = hb >> 3;
  const int tid = threadIdx.x, lane = tid & 63, w = tid >> 6;
  const int rA = lane & 15, g = lane >> 4;
  const int q0w = qt * 128 + w * 32;

  s16x8 qf[2][4];
  #pragma unroll
  for (int qi = 0; qi < 2; ++qi) {
    const unsigned short* qp = q + ((long)(b * Ln + q0w + qi * 16 + rA)) * Hn + h * HDn + g * 8;
    #pragma unroll
    for (int kk = 0; kk < 4; ++kk) qf[qi][kk] = *(const s16x8*)(qp + kk * 32);
  }
  asm volatile("s_waitcnt vmcnt(0)" ::: "memory");   // drain Q: vmcnt now counts only gload16

  f32x4 o[2][8];
  const f32x4 zero = {0.f, 0.f, 0.f, 0.f};
  #pragma unroll
  for (int qi = 0; qi < 2; ++qi)
    #pragma unroll
    for (int nn = 0; nn < 8; ++nn) o[qi][nn] = zero;
  float lrun[2][4];
  #pragma unroll
  for (int qi = 0; qi < 2; ++qi)
    #pragma unroll
    for (int j = 0; j < 4; ++j) lrun[qi][j] = 0.f;
  float m = 0.f;

  const float sc2 = 0.08838834764831845f * 1.4426950408889634f;  // 1/sqrt(128)*log2(e)

  const int krow0 = w * 16 + g;
  const int kc = lane & 15;
  const int vrow0 = w * 32 + (lane >> 3);
  const int vc = lane & 7;

  const unsigned short* kp[4];
  const unsigned short* vp[4];
  #pragma unroll
  for (int qq = 0; qq < 4; ++qq) {
    const int rk = krow0 + qq * 4;
    kp[qq] = k + ((long)(b * Ln + rk)) * Hn + h * HDn + ((kc ^ (rk & 7)) * 8);
    const int rv = vrow0 + qq * 8;
    vp[qq] = vt + ((long)(b * 1024 + h * HDn + rv)) * Ln + ((vc ^ (rv & 7)) * 8);
  }

  auto issueK = [&](int buf) {
    #pragma unroll
    for (int qq = 0; qq < 4; ++qq) {
      gload16(kp[qq], (char*)K2[buf] + w * 4096 + qq * 1024);
      kp[qq] += 64 * Hn;
    }
  };
  auto issueV = [&]() {
    #pragma unroll
    for (int qq = 0; qq < 4; ++qq) {
      gload16(vp[qq], (char*)Vs + w * 4096 + qq * 1024);
      vp[qq] += 64;
    }
  };

  issueK(0);
  asm volatile("s_waitcnt vmcnt(0)" ::: "memory");
  __builtin_amdgcn_s_barrier();

  for (int kvt = 0; kvt < 16; ++kvt) {
    const bool st = (kvt + 1 < 16);
    const char* Kcur = (const char*)K2[kvt & 1];
    issueV();
    if (st) issueK((kvt + 1) & 1);

    f32x4 sacc[2][4];
    #pragma unroll
    for (int qi = 0; qi < 2; ++qi)
      #pragma unroll
      for (int nj = 0; nj < 4; ++nj) sacc[qi][nj] = zero;
    __builtin_amdgcn_s_setprio(1);
    #pragma unroll
    for (int kk = 0; kk < 4; ++kk) {
      #pragma unroll
      for (int nj = 0; nj < 4; ++nj) {
        const int row = nj * 16 + rA;
        const int byt = row * 256 + (((kk * 4 + g) ^ (row & 7)) << 4);
        s16x8 kf = *(const s16x8*)(Kcur + byt);
        sacc[0][nj] = __builtin_amdgcn_mfma_f32_16x16x32_bf16(qf[0][kk], kf, sacc[0][nj], 0, 0, 0);
        sacc[1][nj] = __builtin_amdgcn_mfma_f32_16x16x32_bf16(qf[1][kk], kf, sacc[1][nj], 0, 0, 0);
      }
    }
    __builtin_amdgcn_s_setprio(0);

    float t8[8];
    #pragma unroll
    for (int qi = 0; qi < 2; ++qi)
      #pragma unroll
      for (int nj = 0; nj < 4; ++nj) {
        float s0 = sacc[qi][nj][0] * sc2;
        float s1 = sacc[qi][nj][1] * sc2;
        float s2 = sacc[qi][nj][2] * sc2;
        float s3 = sacc[qi][nj][3] * sc2;
        sacc[qi][nj][0] = s0; sacc[qi][nj][1] = s1;
        sacc[qi][nj][2] = s2; sacc[qi][nj][3] = s3;
        t8[qi * 4 + nj] = fmaxf(fmaxf(s0, s1), fmaxf(s2, s3));
      }
    const float vmax = fmaxf(fmaxf(fmaxf(t8[0], t8[1]), fmaxf(t8[2], t8[3])),
                             fmaxf(fmaxf(t8[4], t8[5]), fmaxf(t8[6], t8[7])));
    if (!__all(vmax <= m + 8.0f)) {
      float mn = vmax;
      #pragma unroll
      for (int mm = 1; mm < 64; mm <<= 1) mn = fmaxf(mn, __shfl_xor(mn, mm, 64));
      const float al = exp2f(m - mn);
      #pragma unroll
      for (int qi = 0; qi < 2; ++qi) {
        #pragma unroll
        for (int nn = 0; nn < 8; ++nn)
          #pragma unroll
          for (int j = 0; j < 4; ++j) o[qi][nn][j] *= al;
        #pragma unroll
        for (int j = 0; j < 4; ++j) lrun[qi][j] *= al;
      }
      m = mn;
    }

    #pragma unroll
    for (int qi = 0; qi < 2; ++qi)
      #pragma unroll
      for (int j = 0; j < 4; ++j) {
        float p0 = exp2f(sacc[qi][0][j] - m);
        float p1 = exp2f(sacc[qi][1][j] - m);
        float p2 = exp2f(sacc[qi][2][j] - m);
        float p3 = exp2f(sacc[qi][3][j] - m);
        lrun[qi][j] += (p0 + p1) + (p2 + p3);
        const int prow = (qi * 16 + g * 4 + j) * 72;
        Ps[w][prow + 0 * 16 + rA] = f2bf(p0);
        Ps[w][prow + 1 * 16 + rA] = f2bf(p1);
        Ps[w][prow + 2 * 16 + rA] = f2bf(p2);
        Ps[w][prow + 3 * 16 + rA] = f2bf(p3);
      }

    if (st) asm volatile("s_waitcnt vmcnt(4)" ::: "memory");
    else    asm volatile("s_waitcnt vmcnt(0)" ::: "memory");
    __builtin_amdgcn_s_barrier();

    s16x8 pf[2][2];
    #pragma unroll
    for (int qi = 0; qi < 2; ++qi)
      #pragma unroll
      for (int kk2 = 0; kk2 < 2; ++kk2)
        pf[qi][kk2] = *(const s16x8*)(&Ps[w][(qi * 16 + rA) * 72 + kk2 * 32 + g * 8]);
    __builtin_amdgcn_s_setprio(1);
    #pragma unroll
    for (int kk2 = 0; kk2 < 2; ++kk2) {
      #pragma unroll
      for (int nn = 0; nn < 8; ++nn) {
        const int row = nn * 16 + rA;
        const int byt = row * 128 + (((kk2 * 4 + g) ^ (row & 7)) << 4);
        s16x8 vf = *(const s16x8*)((const char*)Vs + byt);
        o[0][nn] = __builtin_amdgcn_mfma_f32_16x16x32_bf16(pf[0][kk2], vf, o[0][nn], 0, 0, 0);
        o[1][nn] = __builtin_amdgcn_mfma_f32_16x16x32_bf16(pf[1][kk2], vf, o[1][nn], 0, 0, 0);
      }
    }
    __builtin_amdgcn_s_setprio(0);

    if (st) asm volatile("s_waitcnt vmcnt(0) lgkmcnt(0)" ::: "memory");
    else    asm volatile("s_waitcnt lgkmcnt(0)" ::: "memory");
    __builtin_amdgcn_s_barrier();
  }

  float linv[2][4];
  #pragma unroll
  for (int qi = 0; qi < 2; ++qi)
    #pragma unroll
    for (int j = 0; j < 4; ++j) {
      float l = lrun[qi][j];
      #pragma unroll
      for (int mm = 1; mm < 16; mm <<= 1) l += __shfl_xor(l, mm, 64);
      linv[qi][j] = 1.0f / l;
    }
  #pragma unroll
  for (int qi = 0; qi < 2; ++qi)
    #pragma unroll
    for (int nn = 0; nn < 8; ++nn)
      #pragma unroll
      for (int j = 0; j < 4; ++j) {
        const int row = q0w + qi * 16 + g * 4 + j;
        ctx[((long)(b * Ln + row)) * Hn + h * HDn + nn * 16 + rA] = f2bf(o[qi][nn][j] * linv[qi][j]);
      }
}

// ---------------- diversity ----------------
__global__ __launch_bounds__(256) void div_part_k(const unsigned short* __restrict__ br, float* __restrict__ part)
{
  const int b = blockIdx.y, ch = blockIdx.x;
  const unsigned short* a = br + (long)b * (2L * Sn * Hn);
  const unsigned short* c = a + (long)Sn * Hn;
  const int base = ch * 16384 + threadIdx.x * 8;
  float dot = 0.f, na = 0.f, nb = 0.f;
  #pragma unroll
  for (int i = 0; i < 8; ++i) {
    const int idx = base + i * 2048;
    s16x8 av = *(const s16x8*)(a + idx);
    s16x8 cv = *(const s16x8*)(c + idx);
    #pragma unroll
    for (int e = 0; e < 8; ++e) {
      float fa = bf2f((unsigned short)av[e]);
      float fc = bf2f((unsigned short)cv[e]);
      dot += fa * fc; na += fa * fa; nb += fc * fc;
    }
  }
  #pragma unroll
  for (int mm = 1; mm < 64; mm <<= 1) {
    dot += __shfl_xor(dot, mm, 64);
    na  += __shfl_xor(na, mm, 64);
    nb  += __shfl_xor(nb, mm, 64);
  }
  __shared__ float red[12];
  const int lane = threadIdx.x & 63, w = threadIdx.x >> 6;
  if (lane == 0) { red[w * 3] = dot; red[w * 3 + 1] = na; red[w * 3 + 2] = nb; }
  __syncthreads();
  if (threadIdx.x == 0) {
    float d = 0, x = 0, y = 0;
    for (int i = 0; i < 4; ++i) { d += red[i * 3]; x += red[i * 3 + 1]; y += red[i * 3 + 2]; }
    float* op = part + ((long)(b * 32 + ch)) * 3;
    op[0] = d; op[1] = x; op[2] = y;
  }
}

__global__ __launch_bounds__(64) void div_final_k(const float* __restrict__ part, float* __restrict__ outp)
{
  __shared__ float cosr[8];
  const int tid = threadIdx.x;
  if (tid < 8) {
    float d = 0, x = 0, y = 0;
    for (int i = 0; i < 32; ++i) {
      const float* p = part + ((long)(tid * 32 + i)) * 3;
      d += p[0]; x += p[1]; y += p[2];
    }
    cosr[tid] = d / fmaxf(sqrtf(x) * sqrtf(y), 1e-8f);
  }
  __syncthreads();
  if (tid == 0) {
    float s = 0.f;
    for (int i = 0; i < 8; ++i) s += 1.f - cosr[i];
    outp[0] = s * (1.f / 8.f);
  }
}

// ---------------- launch ----------------
extern "C" void kernel_launch(void* const* d_in, const int* in_sizes, int n_in,
                              void* d_out, int out_size, void* d_ws, size_t ws_size,
                              hipStream_t stream)
{
  (void)in_sizes; (void)n_in; (void)out_size; (void)ws_size;
  const float* hidden   = (const float*)d_in[0];
  const float* router_w = (const float*)d_in[1];
  const float* router_b = (const float*)d_in[2];
  const float* W1 = (const float*)d_in[3];
  const float* b1 = (const float*)d_in[4];
  const float* W2 = (const float*)d_in[5];
  const float* b2 = (const float*)d_in[6];
  const float* Wq = (const float*)d_in[7];
  const float* bq = (const float*)d_in[8];
  const float* Wk = (const float*)d_in[9];
  const float* bk = (const float*)d_in[10];
  const float* Wv = (const float*)d_in[11];
  const float* bv = (const float*)d_in[12];
  const float* Wo = (const float*)d_in[13];
  const float* bo = (const float*)d_in[14];
  float* out = (float*)d_out;

  char* ws = (char*)d_ws;
  float* pooled  = (float*)(ws);
  float* probs   = (float*)(ws + 163840);
  int*   topi    = (int*)  (ws + 164096);
  float* wts     = (float*)(ws + 164352);
  int*   flags   = (int*)  (ws + 164608);
  float* dpart   = (float*)(ws + 164864);
  float* qkvbias = (float*)(ws + 167936);
  unsigned short* hid_bf = (unsigned short*)(ws + 262144);                           // 8.39MB
  unsigned short* Wt     = (unsigned short*)(ws + 262144 + 8388608);                 // 67.1MB
  unsigned short* hbuf   = (unsigned short*)(ws + 262144 + 8388608 + 67108864);      // 67.1MB
  unsigned short* br     = (unsigned short*)(ws + 262144 + 8388608 + 134217728);     // 16.8MB
  unsigned short* wqkvo  = (unsigned short*)(ws + 262144 + 8388608 + 134217728 + 16777216); // 8.4MB
  unsigned short* qb  = Wt;
  unsigned short* kbf = Wt + 8388608;
  unsigned short* vt  = Wt + 16777216;
  unsigned short* ctx = hbuf;
  // ppart (32*8*1024 f32 = 1MB) aliases the Wt region: pool/router complete
  // before the W1 transpose writes Wt (single stream, serialized).
  float* ppart = (float*)Wt;

  // 1. fused convert+pool partials (reads f32 hidden once)
  poolcvt_k<<<dim3(Bn, 32), 256, 0, stream>>>(hidden, hid_bf, ppart);
  pool_final_k<<<dim3(32), 256, 0, stream>>>(ppart, pooled);
  router_k<<<1, 256, 0, stream>>>(pooled, router_w, router_b, probs, topi, wts, flags, out + OUT_COMBINED);

  // 2. weight transposes (4x H*H fused into one launch)
  bias3_k<<<4, 256, 0, stream>>>(bq, bk, bv, qkvbias);
  transpose_k<<<dim3(64, 16, Tn), 256, 0, stream>>>(W1, Wt, Hn, FFn, (long)Hn * FFn, (long)FFn * Hn, flags);
  transpose4_k<<<dim3(16, 16, 4), 256, 0, stream>>>(Wq, Wk, Wv, Wo, wqkvo);

  // 3. FFN1 (gelu): grid (32,2,16) = 1024 blocks
  gemmT_k<1, 0><<<dim3(FFn / 128, Sn / 256, 16), 256, 0, stream>>>(
      hid_bf, Wt, b1, hbuf, FFn, Hn, topi, 2,
      (long)Sn * Hn, 0L, (long)FFn * Hn, FFn, (long)Sn * FFn, nullptr, nullptr);

  // 4. W2 transpose reuses Wt region (W1t dead)
  transpose_k<<<dim3(16, 64, Tn), 256, 0, stream>>>(W2, Wt, FFn, Hn, (long)FFn * Hn, (long)Hn * FFn, flags);

  // 5. FFN2: grid (8,2,16) = 256 blocks
  gemmT_k<0, 0><<<dim3(Hn / 128, Sn / 256, 16), 256, 0, stream>>>(
      hbuf, Wt, b2, br, Hn, FFn, topi, 2,
      0L, (long)Sn * FFn, (long)Hn * FFn, Hn, (long)Sn * Hn, nullptr, nullptr);

  // 6. diversity from branch_out
  div_part_k<<<dim3(32, Bn), 256, 0, stream>>>(br, dpart);
  div_final_k<<<1, 64, 0, stream>>>(dpart, out + OUT_COMBINED + 1);

  // 7. fused QKV projection: grid (24,32) = 768 blocks
  gemmT_k<0, 1><<<dim3(3072 / 128, (Bn * Ln) / 256, 1), 256, 0, stream>>>(
      br, wqkvo, qkvbias, qb, 3072, Hn, nullptr, 0, 0L, 0L, 0L, 0, 0L, nullptr, nullptr);

  // 8. flash attention v3 (1-D grid, XCD-locality remap)
  flash_k<<<dim3(512), 256, 0, stream>>>(qb, kbf, vt, ctx);

  // 9. output projection + combine fused: grid (8,32) = 256 blocks, writes f32 out
  gemmT_k<0, 2><<<dim3(Hn / 128, (Bn * Ln) / 256, 1), 256, 0, stream>>>(
      ctx, wqkvo + 3145728, bo, nullptr, Hn, Hn, nullptr, 0,
      0L, 0L, 0L, 0, 0L, wts, out);
}